// Round 1
// 1387.321 us; speedup vs baseline: 1.1921x; 1.1921x over previous
//
#include <hip/hip_runtime.h>

#define N_NODE 50000
#define N_PRICE 100
#define N_CB 50
#define N_CM 500
#define EMB 128
#define NNZE 1000000
#define NCH 64         /* tv chunks */
#define CS2 832        /* 13 tiles of 64 cols; 64*832 = 53248 >= 50000 */
#define KVPAD 53248
#define RSTRIDE 132    /* 128 num + den + Z + pad */
#define SCAN_T 1024
#define WPAD 72        /* sh_w row stride in bf16 (64 + 8 pad) */
#define E0P 132        /* sh_e0 row stride (fp32), 16B-aligned rows */

typedef __attribute__((ext_vector_type(8))) short bf16x8;
typedef __attribute__((ext_vector_type(4))) float f32x4;

// ---- monotone float<->uint keys for atomic min/max on floats ----
__device__ inline unsigned fkey(float f){
    unsigned b = __float_as_uint(f);
    return (b & 0x80000000u) ? ~b : (b | 0x80000000u);
}
__device__ inline float fdekey(unsigned k){
    unsigned b = (k & 0x80000000u) ? (k & 0x7fffffffu) : ~k;
    return __uint_as_float(b);
}
// fp32 -> bf16 (RNE), bit form
__device__ inline unsigned short f2bf(float f){
    unsigned u = __float_as_uint(f);
    u += 0x7FFFu + ((u >> 16) & 1u);
    return (unsigned short)(u >> 16);
}

// ---------------------------------------------------------------------------
__global__ __launch_bounds__(256) void k_rowsum(
    const float* __restrict__ e_v, const float* __restrict__ e_p,
    const float* __restrict__ e_cb, const float* __restrict__ e_cm,
    float* __restrict__ s_all, unsigned* __restrict__ mm)
{
    if (blockIdx.x == 0 && threadIdx.x < 8)
        mm[threadIdx.x] = (threadIdx.x & 1) ? 0u : 0xFFFFFFFFu;
    int wid  = (blockIdx.x * 256 + threadIdx.x) >> 6;
    int lane = threadIdx.x & 63;
    const int NT = N_NODE + N_PRICE + N_CB + N_CM;
    if (wid >= NT) return;
    const float* src; int lr;
    if (wid < N_NODE)                { src = e_v;  lr = wid; }
    else if (wid < N_NODE+N_PRICE)   { src = e_p;  lr = wid - N_NODE; }
    else if (wid < N_NODE+N_PRICE+N_CB){ src = e_cb; lr = wid - N_NODE - N_PRICE; }
    else                             { src = e_cm; lr = wid - N_NODE - N_PRICE - N_CB; }
    float2 v = ((const float2*)(src + (size_t)lr * EMB))[lane];
    float sum = v.x + v.y;
    #pragma unroll
    for (int o = 32; o > 0; o >>= 1) sum += __shfl_down(sum, o, 64);
    if (lane == 0) s_all[wid] = sum;
}

__global__ __launch_bounds__(256) void k_minmax(
    const float* __restrict__ s_all, unsigned* __restrict__ mm)
{
    __shared__ unsigned smin[4], smax[4];
    int t = threadIdx.x;
    if (t < 4){ smin[t] = 0xFFFFFFFFu; smax[t] = 0u; }
    __syncthreads();
    int gid = blockIdx.x * 256 + t;
    const int NT = N_NODE + N_PRICE + N_CB + N_CM;
    if (gid < NT){
        int ty = (gid < N_NODE) ? 0 :
                 (gid < N_NODE+N_PRICE) ? 1 :
                 (gid < N_NODE+N_PRICE+N_CB) ? 2 : 3;
        unsigned k = fkey(s_all[gid]);
        atomicMin(&smin[ty], k);
        atomicMax(&smax[ty], k);
    }
    __syncthreads();
    if (t < 4){
        if (smin[t] != 0xFFFFFFFFu) atomicMin(&mm[2*t],   smin[t]);
        if (smax[t] != 0u)          atomicMax(&mm[2*t+1], smax[t]);
    }
}

// ---------------------------------------------------------------------------
// CSR build: histogram -> scan -> scatter. Built ONCE per call, used twice.
__global__ __launch_bounds__(256) void k_hist(
    const int* __restrict__ rows, int* __restrict__ counts)
{
    int i = blockIdx.x * 256 + threadIdx.x;
    if (i < NNZE) atomicAdd(&counts[rows[i]], 1);
}

__global__ __launch_bounds__(SCAN_T) void k_scan(
    const int* __restrict__ counts, int* __restrict__ offs, int* __restrict__ cursor)
{
    __shared__ int part[SCAN_T];
    int t = threadIdx.x;
    const int CHUNK = (N_NODE + SCAN_T - 1) / SCAN_T;
    int base = t * CHUNK;
    int s = 0;
    for (int i = 0; i < CHUNK; i++){
        int idx = base + i;
        if (idx < N_NODE) s += counts[idx];
    }
    part[t] = s;
    __syncthreads();
    for (int o = 1; o < SCAN_T; o <<= 1){
        int u = (t >= o) ? part[t - o] : 0;
        __syncthreads();
        part[t] += u;
        __syncthreads();
    }
    int run = part[t] - s;
    for (int i = 0; i < CHUNK; i++){
        int idx = base + i;
        if (idx < N_NODE){
            offs[idx] = run; cursor[idx] = run;
            run += counts[idx];
        }
    }
    if (t == SCAN_T - 1) offs[N_NODE] = run;
}

__global__ __launch_bounds__(256) void k_scatter(
    const int* __restrict__ rows, const int* __restrict__ cols,
    const float* __restrict__ vals, int* __restrict__ cursor,
    int* __restrict__ scol, float* __restrict__ sval)
{
    int i = blockIdx.x * 256 + threadIdx.x;
    if (i < NNZE){
        int r = rows[i];
        int p = atomicAdd(&cursor[r], 1);
        scol[p] = cols[i];
        sval[p] = vals[i];
    }
}

// CSR spmm: one wave per row; lanes cooperatively load nnz, broadcast via shfl.
__global__ __launch_bounds__(256) void k_spmm_csr(
    const int* __restrict__ offs, const int* __restrict__ scol,
    const float* __restrict__ sval, const float* __restrict__ emb,
    float* __restrict__ out)
{
    int row  = (blockIdx.x * 256 + threadIdx.x) >> 6;
    int lane = threadIdx.x & 63;
    if (row >= N_NODE) return;
    int s = offs[row], e = offs[row + 1];
    float2 acc = make_float2(0.f, 0.f);
    for (int base = s; base < e; base += 64){
        int n = base + lane;
        int   cl = (n < e) ? scol[n] : 0;
        float vl = (n < e) ? sval[n] : 0.f;
        int m = e - base; if (m > 64) m = 64;
        for (int j = 0; j < m; j++){
            int   c = __shfl(cl, j, 64);
            float v = __shfl(vl, j, 64);
            float2 em = *(const float2*)(emb + (size_t)c * EMB + lane * 2);
            acc.x += v * em.x; acc.y += v * em.y;
        }
    }
    float* dst = out + (size_t)row * EMB + lane * 2;
    float2 o = *(float2*)dst;
    o.x += acc.x; o.y += acc.y;
    *(float2*)dst = o;
}

// ---------------------------------------------------------------------------
// Tiled transpose-cast: emb [K][EMB] fp32 -> Et [EMB][Kpad] bf16.
// Coalesced reads AND writes via 64x64 LDS tile (old version gathered
// stride-512B, 64 cache lines per wave load).
__global__ __launch_bounds__(256) void k_cast_et_t(
    const float* __restrict__ emb, unsigned short* __restrict__ Et,
    int K, int Kpad)
{
    __shared__ unsigned short tl[64][72];
    int k0 = blockIdx.x * 64, d0 = blockIdx.y * 64;
    int t = threadIdx.x;
    int r = t >> 2, cb = (t & 3) * 16;
    const float* src = emb + (size_t)(k0 + r) * EMB + d0 + cb;
    bool rv = (k0 + r) < K;
    #pragma unroll
    for (int q = 0; q < 4; q++){
        float4 v = rv ? ((const float4*)src)[q] : make_float4(0.f,0.f,0.f,0.f);
        tl[r][cb + q*4 + 0] = f2bf(v.x);
        tl[r][cb + q*4 + 1] = f2bf(v.y);
        tl[r][cb + q*4 + 2] = f2bf(v.z);
        tl[r][cb + q*4 + 3] = f2bf(v.w);
    }
    __syncthreads();
    unsigned short h[16];
    #pragma unroll
    for (int j = 0; j < 16; j++) h[j] = tl[cb + j][r];
    uint4* dst = (uint4*)(Et + (size_t)(d0 + r) * Kpad + k0 + cb);
    dst[0] = make_uint4(((unsigned)h[1]<<16)|h[0], ((unsigned)h[3]<<16)|h[2],
                        ((unsigned)h[5]<<16)|h[4], ((unsigned)h[7]<<16)|h[6]);
    dst[1] = make_uint4(((unsigned)h[9]<<16)|h[8], ((unsigned)h[11]<<16)|h[10],
                        ((unsigned)h[13]<<16)|h[12],((unsigned)h[15]<<16)|h[14]);
}

// ---------------------------------------------------------------------------
// Shared MFMA gate block body (used by the batched small-gate kernel).
// COALESCED adj loads: lane (l) of half-wave (l>>5) loads float2 of 2
// consecutive cols of one row; per instr = 2 rows x 256B = 8 cache lines
// (was 64 lines/instr with the (tid&3)*16+u scatter).
__device__ inline void gate_block_mfma(
    const float* __restrict__ adj, const float* __restrict__ matv,
    const unsigned short* __restrict__ Et, const float* __restrict__ s_src,
    const unsigned* __restrict__ mm2, float* __restrict__ out,
    int K, int Kpad, int nrows, int i0,
    unsigned short* sh_w, float* sh_c, float* sh_M, float* shD, float* shZ)
{
    int tid = threadIdx.x;
    if (tid < 64){
        int i = i0 + tid;
        float c = (i < nrows) ? matv[i] : 0.f;
        float smin = fdekey(mm2[0]), smax = fdekey(mm2[1]);
        sh_c[tid] = c;
        sh_M[tid] = (c >= 0.f) ? c * smax : c * smin;
    }
    __syncthreads();

    int wv = tid >> 6, lane = tid & 63;
    int half = lane >> 5, c2 = (lane & 31) * 2;
    int am = lane & 15, aq = lane >> 4;

    unsigned roff[8];
    float crow[8], Mrow[8], zacc[8], dacc[8];
    #pragma unroll
    for (int i = 0; i < 8; i++){
        int r = wv*16 + i*2 + half;
        int ir = i0 + r; if (ir >= nrows) ir = nrows - 1;
        roff[i] = (unsigned)ir * (unsigned)K;
        crow[i] = sh_c[r]; Mrow[i] = sh_M[r];
        zacc[i] = 0.f; dacc[i] = 0.f;
    }
    f32x4 acc[8];
    #pragma unroll
    for (int n = 0; n < 8; n++) acc[n] = (f32x4){0.f,0.f,0.f,0.f};

    int ntile = Kpad / 64;
    for (int t = 0; t < ntile; t++){
        int k0 = t * 64;
        bool inb = (k0 + c2) < K;       // K even -> covers both elems
        float2 s2 = inb ? *(const float2*)&s_src[k0 + c2] : make_float2(0.f,0.f);
        float2 av[8];
        #pragma unroll
        for (int i = 0; i < 8; i++)
            av[i] = inb ? *(const float2*)&adj[roff[i] + k0 + c2]
                        : make_float2(0.f, 0.f);
        __syncthreads();   // previous MFMA done reading sh_w
        #pragma unroll
        for (int i = 0; i < 8; i++){
            float ex = 0.f, ey = 0.f;
            if (inb){
                ex = __expf(crow[i]*s2.x - Mrow[i]);
                ey = __expf(crow[i]*s2.y - Mrow[i]);
            }
            zacc[i] += ex + ey;
            float wx = ex * av[i].x, wy = ey * av[i].y;
            dacc[i] += wx + wy;
            *(unsigned*)&sh_w[(wv*16 + i*2 + half) * WPAD + c2] =
                (unsigned)f2bf(wx) | ((unsigned)f2bf(wy) << 16);
        }
        __syncthreads();
        #pragma unroll
        for (int ks = 0; ks < 2; ks++){
            bf16x8 afrag = *(const bf16x8*)&sh_w[(wv*16 + am) * WPAD + ks*32 + aq*8];
            #pragma unroll
            for (int n = 0; n < 8; n++){
                bf16x8 bfrag = *(const bf16x8*)&Et[(size_t)(n*16 + am) * Kpad + k0 + ks*32 + aq*8];
                acc[n] = __builtin_amdgcn_mfma_f32_16x16x32_bf16(afrag, bfrag, acc[n], 0, 0, 0);
            }
        }
    }
    #pragma unroll
    for (int o = 1; o <= 16; o <<= 1)
        #pragma unroll
        for (int i = 0; i < 8; i++){
            dacc[i] += __shfl_xor(dacc[i], o, 64);
            zacc[i] += __shfl_xor(zacc[i], o, 64);
        }
    if ((lane & 31) == 0){
        #pragma unroll
        for (int i = 0; i < 8; i++){
            shD[wv*16 + i*2 + half] = dacc[i];
            shZ[wv*16 + i*2 + half] = zacc[i];
        }
    }
    __syncthreads();
    #pragma unroll
    for (int n = 0; n < 8; n++){
        #pragma unroll
        for (int r = 0; r < 4; r++){
            int rl = wv*16 + aq*4 + r;
            int i  = i0 + rl;
            if (i < nrows){
                float inv = 1.f / (shD[rl] + 1e-8f * shZ[rl]);
                out[(size_t)i * EMB + n*16 + am] = acc[n][r] * inv;
            }
        }
    }
}

// Batched small gates: one launch, 6 jobs max.
struct GateJob {
    const float* adj; const float* matv; const unsigned short* Et;
    const float* s; const unsigned* mm2; float* out;
    int K, Kpad, nrows, blk0;
};
struct GateJobs { GateJob j[6]; int njobs; };

__global__ __launch_bounds__(256) void k_gate_batch(GateJobs jobs)
{
    __shared__ unsigned short sh_w[64 * WPAD];
    __shared__ float sh_c[64], sh_M[64], shD[64], shZ[64];
    int b = blockIdx.x;
    int ji = 0;
    for (int q = 1; q < jobs.njobs; q++) if (b >= jobs.j[q].blk0) ji = q;
    GateJob J = jobs.j[ji];
    gate_block_mfma(J.adj, J.matv, J.Et, J.s, J.mm2, J.out, J.K, J.Kpad,
                    J.nrows, (b - J.blk0) * 64, sh_w, sh_c, sh_M, shD, shZ);
}

// ---------------------------------------------------------------------------
// FUSED item update: three V-side intra gates (MFMA, coalesced adj loads) +
// the 4-way inter gate, all per 64-row block.
struct FGate {
    const float* adj; const float* matv; const unsigned short* Et;
    const unsigned* mm2; int K, Kpad, soff;
};
struct FParams { FGate g[3]; };

__global__ __launch_bounds__(256) void k_item_fused(
    FParams P, const float* __restrict__ cv, const float* __restrict__ sseg,
    const float* __restrict__ W, const float* __restrict__ bptr,
    float* __restrict__ out)
{
    __shared__ unsigned short sh_w[64 * WPAD];
    __shared__ float sh_e0[64 * E0P];
    __shared__ float shs[672];           // 650 + zero pad (Kpad overreach safe)
    __shared__ float sh_c[3][64], sh_M[3][64];
    __shared__ float shD[64], shZ[64];
    __shared__ float shWf[128];

    int tid = threadIdx.x;
    int i0  = blockIdx.x * 64;

    for (int j = tid; j < 672; j += 256) shs[j] = (j < 650) ? sseg[j] : 0.f;
    if (tid < 128) shWf[tid] = W[tid];
    if (tid < 192){
        int g = tid >> 6, r = tid & 63;
        int i = i0 + r;
        float c = (i < N_NODE) ? P.g[g].matv[i] : 0.f;
        float smin = fdekey(P.g[g].mm2[0]), smax = fdekey(P.g[g].mm2[1]);
        sh_c[g][r] = c;
        sh_M[g][r] = (c >= 0.f) ? c * smax : c * smin;
    }
    for (int f = tid; f < 64 * 32; f += 256){
        int row = f >> 5, d4 = (f & 31) * 4;
        int i = i0 + row;
        float4 v = (i < N_NODE) ? ((const float4*)(cv + (size_t)i * EMB + d4))[0]
                                : make_float4(0.f,0.f,0.f,0.f);
        ((float4*)&sh_e0[row * E0P + d4])[0] = v;
    }
    __syncthreads();

    int wv = tid >> 6, lane = tid & 63;
    int half = lane >> 5, c2 = (lane & 31) * 2;
    int am = lane & 15, aq = lane >> 4;
    float bb = bptr[0];

    // e0 inter-term: dot with W (butterfly over am lanes), seed run-acc.
    float dp[4] = {0.f,0.f,0.f,0.f};
    #pragma unroll
    for (int n = 0; n < 8; n++)
        #pragma unroll
        for (int r = 0; r < 4; r++)
            dp[r] += sh_e0[(wv*16 + aq*4 + r) * E0P + n*16 + am] * shWf[n*16 + am];
    #pragma unroll
    for (int o = 1; o <= 8; o <<= 1)
        #pragma unroll
        for (int r = 0; r < 4; r++) dp[r] += __shfl_xor(dp[r], o, 64);
    float stot[4];
    #pragma unroll
    for (int r = 0; r < 4; r++) stot[r] = __expf(dp[r] + bb);
    f32x4 run[8];
    #pragma unroll
    for (int n = 0; n < 8; n++)
        #pragma unroll
        for (int r = 0; r < 4; r++)
            run[n][r] = stot[r] * sh_e0[(wv*16 + aq*4 + r) * E0P + n*16 + am];

    for (int g = 0; g < 3; g++){
        FGate G = P.g[g];
        const float* srcs = shs + G.soff;
        unsigned roff[8];
        float crow[8], Mrow[8], zacc[8], dacc[8];
        #pragma unroll
        for (int i = 0; i < 8; i++){
            int r = wv*16 + i*2 + half;
            int ir = i0 + r; if (ir >= N_NODE) ir = N_NODE - 1;
            roff[i] = (unsigned)ir * (unsigned)G.K;
            crow[i] = sh_c[g][r]; Mrow[i] = sh_M[g][r];
            zacc[i] = 0.f; dacc[i] = 0.f;
        }
        f32x4 acc[8];
        #pragma unroll
        for (int n = 0; n < 8; n++) acc[n] = (f32x4){0.f,0.f,0.f,0.f};
        int ntile = G.Kpad >> 6;

        for (int t = 0; t < ntile; t++){
            int k0 = t * 64;
            bool inb = (k0 + c2) < G.K;
            float2 s2 = *(const float2*)&srcs[k0 + c2];   // LDS, padded
            float2 av[8];
            #pragma unroll
            for (int i = 0; i < 8; i++)
                av[i] = inb ? *(const float2*)&G.adj[roff[i] + k0 + c2]
                            : make_float2(0.f, 0.f);
            __syncthreads();   // previous MFMA done reading sh_w
            #pragma unroll
            for (int i = 0; i < 8; i++){
                float ex = 0.f, ey = 0.f;
                if (inb){
                    ex = __expf(crow[i]*s2.x - Mrow[i]);
                    ey = __expf(crow[i]*s2.y - Mrow[i]);
                }
                zacc[i] += ex + ey;
                float wx = ex * av[i].x, wy = ey * av[i].y;
                dacc[i] += wx + wy;
                *(unsigned*)&sh_w[(wv*16 + i*2 + half) * WPAD + c2] =
                    (unsigned)f2bf(wx) | ((unsigned)f2bf(wy) << 16);
            }
            __syncthreads();   // sh_w visible
            #pragma unroll
            for (int ks = 0; ks < 2; ks++){
                bf16x8 afrag = *(const bf16x8*)&sh_w[(wv*16 + am) * WPAD + ks*32 + aq*8];
                #pragma unroll
                for (int n = 0; n < 8; n++){
                    bf16x8 bfrag = *(const bf16x8*)&G.Et[(size_t)(n*16 + am) * G.Kpad + k0 + ks*32 + aq*8];
                    acc[n] = __builtin_amdgcn_mfma_f32_16x16x32_bf16(afrag, bfrag, acc[n], 0, 0, 0);
                }
            }
        }
        #pragma unroll
        for (int o = 1; o <= 16; o <<= 1)
            #pragma unroll
            for (int i = 0; i < 8; i++){
                dacc[i] += __shfl_xor(dacc[i], o, 64);
                zacc[i] += __shfl_xor(zacc[i], o, 64);
            }
        if ((lane & 31) == 0){
            #pragma unroll
            for (int i = 0; i < 8; i++){
                shD[wv*16 + i*2 + half] = dacc[i];
                shZ[wv*16 + i*2 + half] = zacc[i];
            }
        }
        __syncthreads();
        float inv[4];
        #pragma unroll
        for (int r = 0; r < 4; r++){
            int rl = wv*16 + aq*4 + r;
            inv[r] = 1.f / (shD[rl] + 1e-8f * shZ[rl]);
        }
        float dpg[4] = {0.f,0.f,0.f,0.f};
        #pragma unroll
        for (int n = 0; n < 8; n++)
            #pragma unroll
            for (int r = 0; r < 4; r++){
                acc[n][r] *= inv[r];
                dpg[r] += acc[n][r] * shWf[n*16 + am];
            }
        #pragma unroll
        for (int o = 1; o <= 8; o <<= 1)
            #pragma unroll
            for (int r = 0; r < 4; r++) dpg[r] += __shfl_xor(dpg[r], o, 64);
        #pragma unroll
        for (int r = 0; r < 4; r++){
            float sg = __expf(dpg[r] + bb);
            stot[r] += sg;
            #pragma unroll
            for (int n = 0; n < 8; n++) run[n][r] += sg * acc[n][r];
        }
    }
    float invs[4];
    #pragma unroll
    for (int r = 0; r < 4; r++) invs[r] = 1.f / stot[r];
    #pragma unroll
    for (int n = 0; n < 8; n++)
        #pragma unroll
        for (int r = 0; r < 4; r++){
            int i = i0 + wv*16 + aq*4 + r;
            if (i < N_NODE) out[(size_t)i * EMB + n*16 + am] = run[n][r] * invs[r];
        }
}

// ---------------------------------------------------------------------------
// transposed-side intra gate (MFMA), phase 1: 64 rows/block, chunk of CS2
// item-cols, writes partial (num[128], den, Z) per (row, chunk).
// Coalesced adj loads + s_v staged in LDS.
__global__ __launch_bounds__(256) void k_intra_tv_mfma(
    const float* __restrict__ adj, const float* __restrict__ matv,
    const unsigned short* __restrict__ Et, const float* __restrict__ s_v,
    const unsigned* __restrict__ mm2,
    float* __restrict__ part, int baseR, int rows)
{
    __shared__ unsigned short sh_w[64 * WPAD];
    __shared__ float sh_c[64], sh_M[64], sh_s[CS2];
    int tid = threadIdx.x;
    int rb = blockIdx.x / NCH;
    int ch = blockIdx.x % NCH;
    int r0 = rb * 64;
    if (tid < 64){
        int r = r0 + tid;
        float c = (r < rows) ? matv[r] : 0.f;
        float smin = fdekey(mm2[0]), smax = fdekey(mm2[1]);
        sh_c[tid] = c;
        sh_M[tid] = (c >= 0.f) ? c * smax : c * smin;
    }
    for (int j = tid; j < CS2; j += 256){
        int gj = ch * CS2 + j;
        sh_s[j] = (gj < N_NODE) ? s_v[gj] : 0.f;
    }
    __syncthreads();

    int wv = tid >> 6, lane = tid & 63;
    int half = lane >> 5, c2 = (lane & 31) * 2;
    int am = lane & 15, aq = lane >> 4;

    unsigned roff[8];
    float crow[8], Mrow[8], zacc[8], dacc[8];
    #pragma unroll
    for (int i = 0; i < 8; i++){
        int r = wv*16 + i*2 + half;
        int rr = r0 + r; if (rr >= rows) rr = rows - 1;
        roff[i] = (unsigned)rr * (unsigned)N_NODE;
        crow[i] = sh_c[r]; Mrow[i] = sh_M[r];
        zacc[i] = 0.f; dacc[i] = 0.f;
    }
    f32x4 acc[8];
    #pragma unroll
    for (int n = 0; n < 8; n++) acc[n] = (f32x4){0.f,0.f,0.f,0.f};

    for (int t = 0; t < CS2 / 64; t++){
        int k0g = ch * CS2 + t * 64;
        int k0l = t * 64;
        bool inb = (k0g + c2) < N_NODE;
        float2 s2 = *(const float2*)&sh_s[k0l + c2];
        float2 av[8];
        #pragma unroll
        for (int i = 0; i < 8; i++)
            av[i] = inb ? *(const float2*)&adj[roff[i] + k0g + c2]
                        : make_float2(0.f, 0.f);
        __syncthreads();
        #pragma unroll
        for (int i = 0; i < 8; i++){
            float ex = 0.f, ey = 0.f;
            if (inb){
                ex = __expf(crow[i]*s2.x - Mrow[i]);
                ey = __expf(crow[i]*s2.y - Mrow[i]);
            }
            zacc[i] += ex + ey;
            float wx = ex * av[i].x, wy = ey * av[i].y;
            dacc[i] += wx + wy;
            *(unsigned*)&sh_w[(wv*16 + i*2 + half) * WPAD + c2] =
                (unsigned)f2bf(wx) | ((unsigned)f2bf(wy) << 16);
        }
        __syncthreads();
        #pragma unroll
        for (int ks = 0; ks < 2; ks++){
            bf16x8 afrag = *(const bf16x8*)&sh_w[(wv*16 + am) * WPAD + ks*32 + aq*8];
            #pragma unroll
            for (int n = 0; n < 8; n++){
                bf16x8 bfrag = *(const bf16x8*)&Et[(size_t)(n*16 + am) * KVPAD + k0g + ks*32 + aq*8];
                acc[n] = __builtin_amdgcn_mfma_f32_16x16x32_bf16(afrag, bfrag, acc[n], 0, 0, 0);
            }
        }
    }
    #pragma unroll
    for (int o = 1; o <= 16; o <<= 1)
        #pragma unroll
        for (int i = 0; i < 8; i++){
            dacc[i] += __shfl_xor(dacc[i], o, 64);
            zacc[i] += __shfl_xor(zacc[i], o, 64);
        }
    if ((lane & 31) == 0){
        #pragma unroll
        for (int i = 0; i < 8; i++){
            int rr = r0 + wv*16 + i*2 + half;
            if (rr < rows){
                float* d2 = part + ((size_t)(baseR + rr) * NCH + ch) * RSTRIDE;
                d2[128] = dacc[i]; d2[129] = zacc[i];
            }
        }
    }
    #pragma unroll
    for (int n = 0; n < 8; n++){
        #pragma unroll
        for (int r = 0; r < 4; r++){
            int rl = wv*16 + aq*4 + r;
            int rr = r0 + rl;
            if (rr < rows){
                float* d2 = part + ((size_t)(baseR + rr) * NCH + ch) * RSTRIDE;
                d2[n*16 + am] = acc[n][r];
            }
        }
    }
}

// ---------------------------------------------------------------------------
// Batched phase-2: reduce big-gate partials over NCH chunks + 4-way inter
// gate from precomputed small-gate buffers. One 128-thr block per row.
struct RIJob {
    const float* e0; float* out; const float* gA; const float* gB;
    const float* W; const float* b; int baseR; int nrows; int row0;
};
struct RIJobs { RIJob j[3]; int njobs; };

__global__ __launch_bounds__(128) void k_reduce_inter(
    RIJobs jobs, const float* __restrict__ part)
{
    __shared__ float sh[4][EMB];
    __shared__ float shW[EMB];
    int b = blockIdx.x;
    int ji = 0;
    for (int q = 1; q < jobs.njobs; q++) if (b >= jobs.j[q].row0) ji = q;
    RIJob J = jobs.j[ji];
    int r = b - J.row0;
    int d = threadIdx.x;
    float num = 0.f, den = 0.f, Z = 0.f;
    for (int c = 0; c < NCH; c++){
        const float* p = part + ((size_t)(J.baseR + r) * NCH + c) * RSTRIDE;
        num += p[d]; den += p[128]; Z += p[129];
    }
    sh[1][d] = num / (den + 1e-8f * Z);
    sh[0][d] = J.e0[(size_t)r * EMB + d];
    sh[2][d] = J.gA[(size_t)r * EMB + d];
    sh[3][d] = J.gB[(size_t)r * EMB + d];
    shW[d] = J.W[d];
    __syncthreads();
    float dots[4];
    #pragma unroll
    for (int g = 0; g < 4; g++){
        float acc = 0.f;
        for (int k = 0; k < EMB; k++) acc += sh[g][k] * shW[k];
        dots[g] = acc;
    }
    float bb = J.b[0];
    float s0 = __expf(dots[0] + bb), s1 = __expf(dots[1] + bb);
    float s2 = __expf(dots[2] + bb), s3 = __expf(dots[3] + bb);
    float inv = 1.f / (s0 + s1 + s2 + s3);
    J.out[(size_t)r * EMB + d] =
        (s0*sh[0][d] + s1*sh[1][d] + s2*sh[2][d] + s3*sh[3][d]) * inv;
}

// ---------------------------------------------------------------------------
extern "C" void kernel_launch(void* const* d_in, const int* in_sizes, int n_in,
                              void* d_out, int out_size, void* d_ws, size_t ws_size,
                              hipStream_t stream)
{
    const int*   adj_idx  = (const int*)d_in[0];
    const float* adj_val  = (const float*)d_in[1];
    const float* a_pv   = (const float*)d_in[2];
    const float* a_vp   = (const float*)d_in[3];
    const float* a_pcb  = (const float*)d_in[4];
    const float* a_cbp  = (const float*)d_in[5];
    const float* a_cbv  = (const float*)d_in[6];
    const float* a_vcb  = (const float*)d_in[7];
    const float* a_pcm  = (const float*)d_in[8];
    const float* a_cmp  = (const float*)d_in[9];
    const float* a_cmv  = (const float*)d_in[10];
    const float* a_vcm  = (const float*)d_in[11];
    const float* a_cbcm = (const float*)d_in[12];
    const float* a_cmcb = (const float*)d_in[13];
    const float* in_item = (const float*)d_in[14];
    const float* in_pri  = (const float*)d_in[15];
    const float* in_cb   = (const float*)d_in[16];
    const float* in_cm   = (const float*)d_in[17];
    const float* m_vp  = (const float*)d_in[18];
    const float* m_vcb = (const float*)d_in[19];
    const float* m_vcm = (const float*)d_in[20];
    const float* m_pv  = (const float*)d_in[21];
    const float* m_pcb = (const float*)d_in[22];
    const float* m_pcm = (const float*)d_in[23];
    const float* m_cbp = (const float*)d_in[24];
    const float* m_cbv = (const float*)d_in[25];
    const float* m_cbcm= (const float*)d_in[26];
    const float* m_cmp = (const float*)d_in[27];
    const float* m_cmv = (const float*)d_in[28];
    const float* m_cmcb= (const float*)d_in[29];
    const float* Wi = (const float*)d_in[30]; const float* bi = (const float*)d_in[31];
    const float* Wp = (const float*)d_in[32]; const float* bp = (const float*)d_in[33];
    const float* Wcb= (const float*)d_in[34]; const float* bcb= (const float*)d_in[35];
    const float* Wcm= (const float*)d_in[36]; const float* bcm= (const float*)d_in[37];

    float* ws = (float*)d_ws;
    size_t off = 0;
    auto alloc = [&](size_t n){ float* p = ws + off; off += (n + 63) & ~(size_t)63; return p; };
    float* buf_item = alloc((size_t)N_NODE * EMB);
    float* buf_pri  = alloc((size_t)N_PRICE * EMB);
    float* buf_cb   = alloc((size_t)N_CB * EMB);
    float* buf_cm   = alloc((size_t)N_CM * EMB);
    float* s_all    = alloc(N_NODE + N_PRICE + N_CB + N_CM);
    unsigned* mm    = (unsigned*)alloc(64);
    float* g1 = alloc((size_t)N_NODE * EMB);
    float* g3 = alloc((size_t)N_NODE * EMB);
    float* part = g1;                       // 650*64*132 = 5.49M floats, alias g1
    unsigned short* et_v = (unsigned short*)g3;  // 13.6 MB, alias g3
    int*   counts = (int*)alloc(N_NODE + 64);
    int*   offs   = (int*)alloc(N_NODE + 64);
    int*   cursor = (int*)alloc(N_NODE + 64);
    int*   scol   = (int*)alloc(NNZE);
    float* sval   = alloc(NNZE);
    unsigned short* et_p  = (unsigned short*)alloc(EMB * 128 / 2);
    unsigned short* et_cb = (unsigned short*)alloc(EMB * 64 / 2);
    unsigned short* et_cm = (unsigned short*)alloc(EMB * 512 / 2);
    float* g_pcb  = alloc((size_t)N_PRICE * EMB);
    float* g_pcm  = alloc((size_t)N_PRICE * EMB);
    float* g_cbp  = alloc((size_t)N_CB * EMB);
    float* g_cbcm = alloc((size_t)N_CB * EMB);
    float* g_cmp  = alloc((size_t)N_CM * EMB);
    float* g_cmcb = alloc((size_t)N_CM * EMB);

    float* out_item = (float*)d_out;
    float* out_pri  = (float*)d_out + (size_t)N_NODE * EMB;

    const float* s_v  = s_all;
    const float* s_p  = s_all + N_NODE;
    const float* s_cb = s_all + N_NODE + N_PRICE;
    const float* s_cm = s_all + N_NODE + N_PRICE + N_CB;

    const int totr = N_NODE + N_PRICE + N_CB + N_CM;

    // ---- CSR build (once; adjacency is layer-invariant) ----
    hipMemsetAsync(counts, 0, N_NODE * sizeof(int), stream);
    k_hist<<<(NNZE + 255)/256, 256, 0, stream>>>(adj_idx, counts);
    k_scan<<<1, SCAN_T, 0, stream>>>(counts, offs, cursor);
    k_scatter<<<(NNZE + 255)/256, 256, 0, stream>>>(adj_idx, adj_idx + NNZE,
                                                    adj_val, cursor, scol, sval);

    for (int layer = 0; layer < 2; layer++){
        const float* cv  = layer ? buf_item : in_item;
        const float* cp  = layer ? buf_pri  : in_pri;
        const float* ccb = layer ? buf_cb   : in_cb;
        const float* ccm = layer ? buf_cm   : in_cm;
        float* ov = layer ? out_item : buf_item;
        float* op = layer ? out_pri  : buf_pri;

        k_rowsum<<<(totr + 3)/4, 256, 0, stream>>>(cv, cp, ccb, ccm, s_all, mm);
        k_minmax<<<(totr + 255)/256, 256, 0, stream>>>(s_all, mm);

        // bf16 transposed operands for p/cb/cm-source gates (tiled transpose)
        k_cast_et_t<<<dim3(2, 2), 256, 0, stream>>>(cp,  et_p,  N_PRICE, 128);
        k_cast_et_t<<<dim3(1, 2), 256, 0, stream>>>(ccb, et_cb, N_CB,    64);
        k_cast_et_t<<<dim3(8, 2), 256, 0, stream>>>(ccm, et_cm, N_CM,    512);

        // batched small gates (MFMA)
        GateJobs gj{};
        int nb = 0, nj = 0;
        auto addjob = [&](const float* adj_, const float* matv_,
                          const unsigned short* Et_, const float* s_,
                          const unsigned* mm2_, float* out_,
                          int K_, int Kpad_, int nrows_){
            gj.j[nj] = GateJob{adj_, matv_, Et_, s_, mm2_, out_,
                               K_, Kpad_, nrows_, nb};
            nb += (nrows_ + 63) / 64; nj++;
        };
        addjob(a_pcb, m_pcb, et_cb, s_cb, mm+4, g_pcb, N_CB,    64, N_PRICE);
        addjob(a_pcm, m_pcm, et_cm, s_cm, mm+6, g_pcm, N_CM,   512, N_PRICE);
        if (layer == 0){
            addjob(a_cbp,  m_cbp,  et_p,  s_p,  mm+2, g_cbp,  N_PRICE, 128, N_CB);
            addjob(a_cbcm, m_cbcm, et_cm, s_cm, mm+6, g_cbcm, N_CM,   512, N_CB);
            addjob(a_cmp,  m_cmp,  et_p,  s_p,  mm+2, g_cmp,  N_PRICE, 128, N_CM);
            addjob(a_cmcb, m_cmcb, et_cb, s_cb, mm+4, g_cmcb, N_CB,    64, N_CM);
        }
        gj.njobs = nj;
        k_gate_batch<<<nb, 256, 0, stream>>>(gj);

        // fused item update (3 intra gates + inter gate)
        FParams fp{};
        fp.g[0] = FGate{a_vp,  m_vp,  et_p,  mm+2, N_PRICE, 128, 0};
        fp.g[1] = FGate{a_vcb, m_vcb, et_cb, mm+4, N_CB,    64,  100};
        fp.g[2] = FGate{a_vcm, m_vcm, et_cm, mm+6, N_CM,    512, 150};
        k_item_fused<<<(N_NODE + 63)/64, 256, 0, stream>>>(
            fp, cv, s_all + N_NODE, Wi, bi, ov);

        k_spmm_csr<<<(N_NODE*64 + 255)/256, 256, 0, stream>>>(offs, scol, sval, cv, ov);

        // item-side bf16 transposed operand (aliases g3, now dead)
        k_cast_et_t<<<dim3(KVPAD/64, 2), 256, 0, stream>>>(cv, et_v, N_NODE, KVPAD);

        k_intra_tv_mfma<<<((N_PRICE + 63)/64) * NCH, 256, 0, stream>>>(
            a_pv, m_pv, et_v, s_v, mm + 0, part, 0, N_PRICE);
        if (layer == 0){
            k_intra_tv_mfma<<<((N_CB + 63)/64) * NCH, 256, 0, stream>>>(
                a_cbv, m_cbv, et_v, s_v, mm + 0, part, N_PRICE, N_CB);
            k_intra_tv_mfma<<<((N_CM + 63)/64) * NCH, 256, 0, stream>>>(
                a_cmv, m_cmv, et_v, s_v, mm + 0, part, N_PRICE + N_CB, N_CM);
        }

        // batched phase-2 reduce + inter
        RIJobs rj{};
        rj.j[0] = RIJob{cp, op, g_pcb, g_pcm, Wp, bp, 0, N_PRICE, 0};
        int nrows_tot = N_PRICE;
        int njr = 1;
        if (layer == 0){
            rj.j[1] = RIJob{ccb, buf_cb, g_cbp, g_cbcm, Wcb, bcb,
                            N_PRICE, N_CB, nrows_tot};
            nrows_tot += N_CB; njr++;
            rj.j[2] = RIJob{ccm, buf_cm, g_cmp, g_cmcb, Wcm, bcm,
                            N_PRICE + N_CB, N_CM, nrows_tot};
            nrows_tot += N_CM; njr++;
        }
        rj.njobs = njr;
        k_reduce_inter<<<nrows_tot, 128, 0, stream>>>(rj, part);
    }
    (void)in_sizes; (void)n_in; (void)out_size; (void)ws_size;
}

// Round 2
// 1272.879 us; speedup vs baseline: 1.2993x; 1.0899x over previous
//
#include <hip/hip_runtime.h>

#define N_NODE 50000
#define N_PRICE 100
#define N_CB 50
#define N_CM 500
#define EMB 128
#define NNZE 1000000
#define NCH 64         /* tv chunks */
#define CS2 832        /* 13 tiles of 64 cols; 64*832 = 53248 >= 50000 */
#define KVPAD 53248
#define RSTRIDE 132    /* 128 num + den + Z + pad */
#define SCAN_T 1024
#define WPAD 72        /* sh_w row stride in bf16 (64 + 8 pad) */
#define E0P 132        /* sh_e0 row stride (fp32), 16B-aligned rows */

typedef __attribute__((ext_vector_type(8))) short bf16x8;
typedef __attribute__((ext_vector_type(4))) float f32x4;

// ---- monotone float<->uint keys for atomic min/max on floats ----
__device__ inline unsigned fkey(float f){
    unsigned b = __float_as_uint(f);
    return (b & 0x80000000u) ? ~b : (b | 0x80000000u);
}
__device__ inline float fdekey(unsigned k){
    unsigned b = (k & 0x80000000u) ? (k & 0x7fffffffu) : ~k;
    return __uint_as_float(b);
}
// fp32 -> bf16 (RNE), bit form
__device__ inline unsigned short f2bf(float f){
    unsigned u = __float_as_uint(f);
    u += 0x7FFFu + ((u >> 16) & 1u);
    return (unsigned short)(u >> 16);
}

// ---------------------------------------------------------------------------
__global__ __launch_bounds__(256) void k_rowsum(
    const float* __restrict__ e_v, const float* __restrict__ e_p,
    const float* __restrict__ e_cb, const float* __restrict__ e_cm,
    float* __restrict__ s_all, unsigned* __restrict__ mm)
{
    if (blockIdx.x == 0 && threadIdx.x < 8)
        mm[threadIdx.x] = (threadIdx.x & 1) ? 0u : 0xFFFFFFFFu;
    int wid  = (blockIdx.x * 256 + threadIdx.x) >> 6;
    int lane = threadIdx.x & 63;
    const int NT = N_NODE + N_PRICE + N_CB + N_CM;
    if (wid >= NT) return;
    const float* src; int lr;
    if (wid < N_NODE)                { src = e_v;  lr = wid; }
    else if (wid < N_NODE+N_PRICE)   { src = e_p;  lr = wid - N_NODE; }
    else if (wid < N_NODE+N_PRICE+N_CB){ src = e_cb; lr = wid - N_NODE - N_PRICE; }
    else                             { src = e_cm; lr = wid - N_NODE - N_PRICE - N_CB; }
    float2 v = ((const float2*)(src + (size_t)lr * EMB))[lane];
    float sum = v.x + v.y;
    #pragma unroll
    for (int o = 32; o > 0; o >>= 1) sum += __shfl_down(sum, o, 64);
    if (lane == 0) s_all[wid] = sum;
}

__global__ __launch_bounds__(256) void k_minmax(
    const float* __restrict__ s_all, unsigned* __restrict__ mm)
{
    __shared__ unsigned smin[4], smax[4];
    int t = threadIdx.x;
    if (t < 4){ smin[t] = 0xFFFFFFFFu; smax[t] = 0u; }
    __syncthreads();
    int gid = blockIdx.x * 256 + t;
    const int NT = N_NODE + N_PRICE + N_CB + N_CM;
    if (gid < NT){
        int ty = (gid < N_NODE) ? 0 :
                 (gid < N_NODE+N_PRICE) ? 1 :
                 (gid < N_NODE+N_PRICE+N_CB) ? 2 : 3;
        unsigned k = fkey(s_all[gid]);
        atomicMin(&smin[ty], k);
        atomicMax(&smax[ty], k);
    }
    __syncthreads();
    if (t < 4){
        if (smin[t] != 0xFFFFFFFFu) atomicMin(&mm[2*t],   smin[t]);
        if (smax[t] != 0u)          atomicMax(&mm[2*t+1], smax[t]);
    }
}

// ---------------------------------------------------------------------------
// CSR build: histogram -> scan -> scatter. Built ONCE per call, used twice.
__global__ __launch_bounds__(256) void k_hist(
    const int* __restrict__ rows, int* __restrict__ counts)
{
    int i = blockIdx.x * 256 + threadIdx.x;
    if (i < NNZE) atomicAdd(&counts[rows[i]], 1);
}

__global__ __launch_bounds__(SCAN_T) void k_scan(
    const int* __restrict__ counts, int* __restrict__ offs, int* __restrict__ cursor)
{
    __shared__ int part[SCAN_T];
    int t = threadIdx.x;
    const int CHUNK = (N_NODE + SCAN_T - 1) / SCAN_T;
    int base = t * CHUNK;
    int s = 0;
    for (int i = 0; i < CHUNK; i++){
        int idx = base + i;
        if (idx < N_NODE) s += counts[idx];
    }
    part[t] = s;
    __syncthreads();
    for (int o = 1; o < SCAN_T; o <<= 1){
        int u = (t >= o) ? part[t - o] : 0;
        __syncthreads();
        part[t] += u;
        __syncthreads();
    }
    int run = part[t] - s;
    for (int i = 0; i < CHUNK; i++){
        int idx = base + i;
        if (idx < N_NODE){
            offs[idx] = run; cursor[idx] = run;
            run += counts[idx];
        }
    }
    if (t == SCAN_T - 1) offs[N_NODE] = run;
}

__global__ __launch_bounds__(256) void k_scatter(
    const int* __restrict__ rows, const int* __restrict__ cols,
    const float* __restrict__ vals, int* __restrict__ cursor,
    int* __restrict__ scol, float* __restrict__ sval)
{
    int i = blockIdx.x * 256 + threadIdx.x;
    if (i < NNZE){
        int r = rows[i];
        int p = atomicAdd(&cursor[r], 1);
        scol[p] = cols[i];
        sval[p] = vals[i];
    }
}

// CSR spmm: one wave per row; lanes cooperatively load nnz, broadcast via shfl.
__global__ __launch_bounds__(256) void k_spmm_csr(
    const int* __restrict__ offs, const int* __restrict__ scol,
    const float* __restrict__ sval, const float* __restrict__ emb,
    float* __restrict__ out)
{
    int row  = (blockIdx.x * 256 + threadIdx.x) >> 6;
    int lane = threadIdx.x & 63;
    if (row >= N_NODE) return;
    int s = offs[row], e = offs[row + 1];
    float2 acc = make_float2(0.f, 0.f);
    for (int base = s; base < e; base += 64){
        int n = base + lane;
        int   cl = (n < e) ? scol[n] : 0;
        float vl = (n < e) ? sval[n] : 0.f;
        int m = e - base; if (m > 64) m = 64;
        for (int j = 0; j < m; j++){
            int   c = __shfl(cl, j, 64);
            float v = __shfl(vl, j, 64);
            float2 em = *(const float2*)(emb + (size_t)c * EMB + lane * 2);
            acc.x += v * em.x; acc.y += v * em.y;
        }
    }
    float* dst = out + (size_t)row * EMB + lane * 2;
    float2 o = *(float2*)dst;
    o.x += acc.x; o.y += acc.y;
    *(float2*)dst = o;
}

// ---------------------------------------------------------------------------
// Tiled transpose-cast: emb [K][EMB] fp32 -> Et [EMB][Kpad] bf16.
__global__ __launch_bounds__(256) void k_cast_et_t(
    const float* __restrict__ emb, unsigned short* __restrict__ Et,
    int K, int Kpad)
{
    __shared__ unsigned short tl[64][72];
    int k0 = blockIdx.x * 64, d0 = blockIdx.y * 64;
    int t = threadIdx.x;
    int r = t >> 2, cb = (t & 3) * 16;
    const float* src = emb + (size_t)(k0 + r) * EMB + d0 + cb;
    bool rv = (k0 + r) < K;
    #pragma unroll
    for (int q = 0; q < 4; q++){
        float4 v = rv ? ((const float4*)src)[q] : make_float4(0.f,0.f,0.f,0.f);
        tl[r][cb + q*4 + 0] = f2bf(v.x);
        tl[r][cb + q*4 + 1] = f2bf(v.y);
        tl[r][cb + q*4 + 2] = f2bf(v.z);
        tl[r][cb + q*4 + 3] = f2bf(v.w);
    }
    __syncthreads();
    unsigned short h[16];
    #pragma unroll
    for (int j = 0; j < 16; j++) h[j] = tl[cb + j][r];
    uint4* dst = (uint4*)(Et + (size_t)(d0 + r) * Kpad + k0 + cb);
    dst[0] = make_uint4(((unsigned)h[1]<<16)|h[0], ((unsigned)h[3]<<16)|h[2],
                        ((unsigned)h[5]<<16)|h[4], ((unsigned)h[7]<<16)|h[6]);
    dst[1] = make_uint4(((unsigned)h[9]<<16)|h[8], ((unsigned)h[11]<<16)|h[10],
                        ((unsigned)h[13]<<16)|h[12],((unsigned)h[15]<<16)|h[14]);
}

// ---------------------------------------------------------------------------
// Shared MFMA gate block body. BARRIER-FREE tile loop: sh_w rows
// [wv*16, wv*16+16) are written AND read only by wave wv (wave-private), so
// no __syncthreads in the loop -> no compiler-forced vmcnt(0) drain of the
// adjacency loads. One-tile register prefetch (avN) hides HBM latency under
// the exp+MFMA body of the current tile.
__device__ inline void gate_block_mfma(
    const float* __restrict__ adj, const float* __restrict__ matv,
    const unsigned short* __restrict__ Et, const float* __restrict__ s_src,
    const unsigned* __restrict__ mm2, float* __restrict__ out,
    int K, int Kpad, int nrows, int i0,
    unsigned short* sh_w, float* sh_c, float* sh_M, float* shD, float* shZ)
{
    int tid = threadIdx.x;
    if (tid < 64){
        int i = i0 + tid;
        float c = (i < nrows) ? matv[i] : 0.f;
        float smin = fdekey(mm2[0]), smax = fdekey(mm2[1]);
        sh_c[tid] = c;
        sh_M[tid] = (c >= 0.f) ? c * smax : c * smin;
    }
    __syncthreads();    // only barrier: sh_c/sh_M staging is cross-wave

    int wv = tid >> 6, lane = tid & 63;
    int half = lane >> 5, c2 = (lane & 31) * 2;
    int am = lane & 15, aq = lane >> 4;

    unsigned roff[8];
    float crow[8], Mrow[8], zacc[8], dacc[8];
    #pragma unroll
    for (int i = 0; i < 8; i++){
        int r = wv*16 + i*2 + half;
        int ir = i0 + r; if (ir >= nrows) ir = nrows - 1;
        roff[i] = (unsigned)ir * (unsigned)K;
        crow[i] = sh_c[r]; Mrow[i] = sh_M[r];
        zacc[i] = 0.f; dacc[i] = 0.f;
    }
    f32x4 acc[8];
    #pragma unroll
    for (int n = 0; n < 8; n++) acc[n] = (f32x4){0.f,0.f,0.f,0.f};

    int ntile = Kpad / 64;
    float2 avC[8], avN[8], s2C, s2N;
    bool inbC = (c2 < K), inbN;
    s2C = inbC ? *(const float2*)&s_src[c2] : make_float2(0.f, 0.f);
    #pragma unroll
    for (int i = 0; i < 8; i++)
        avC[i] = inbC ? *(const float2*)&adj[roff[i] + c2] : make_float2(0.f, 0.f);

    for (int t = 0; t < ntile; t++){
        int k0 = t * 64, k0n = k0 + 64;
        inbN = (t + 1 < ntile) && (k0n + c2 < K);
        s2N = inbN ? *(const float2*)&s_src[k0n + c2] : make_float2(0.f, 0.f);
        #pragma unroll
        for (int i = 0; i < 8; i++)
            avN[i] = inbN ? *(const float2*)&adj[roff[i] + k0n + c2]
                          : make_float2(0.f, 0.f);

        #pragma unroll
        for (int i = 0; i < 8; i++){
            float ex = 0.f, ey = 0.f;
            if (inbC){
                ex = __expf(crow[i]*s2C.x - Mrow[i]);
                ey = __expf(crow[i]*s2C.y - Mrow[i]);
            }
            zacc[i] += ex + ey;
            float wx = ex * avC[i].x, wy = ey * avC[i].y;
            dacc[i] += wx + wy;
            *(unsigned*)&sh_w[(wv*16 + i*2 + half) * WPAD + c2] =
                (unsigned)f2bf(wx) | ((unsigned)f2bf(wy) << 16);
        }
        #pragma unroll
        for (int ks = 0; ks < 2; ks++){
            bf16x8 afrag = *(const bf16x8*)&sh_w[(wv*16 + am) * WPAD + ks*32 + aq*8];
            #pragma unroll
            for (int n = 0; n < 8; n++){
                bf16x8 bfrag = *(const bf16x8*)&Et[(size_t)(n*16 + am) * Kpad + k0 + ks*32 + aq*8];
                acc[n] = __builtin_amdgcn_mfma_f32_16x16x32_bf16(afrag, bfrag, acc[n], 0, 0, 0);
            }
        }
        inbC = inbN; s2C = s2N;
        #pragma unroll
        for (int i = 0; i < 8; i++) avC[i] = avN[i];
    }
    #pragma unroll
    for (int o = 1; o <= 16; o <<= 1)
        #pragma unroll
        for (int i = 0; i < 8; i++){
            dacc[i] += __shfl_xor(dacc[i], o, 64);
            zacc[i] += __shfl_xor(zacc[i], o, 64);
        }
    if ((lane & 31) == 0){
        #pragma unroll
        for (int i = 0; i < 8; i++){
            shD[wv*16 + i*2 + half] = dacc[i];
            shZ[wv*16 + i*2 + half] = zacc[i];
        }
    }
    // shD/shZ rows are wave-private too: no barrier, in-wave lgkm suffices.
    #pragma unroll
    for (int n = 0; n < 8; n++){
        #pragma unroll
        for (int r = 0; r < 4; r++){
            int rl = wv*16 + aq*4 + r;
            int i  = i0 + rl;
            if (i < nrows){
                float inv = 1.f / (shD[rl] + 1e-8f * shZ[rl]);
                out[(size_t)i * EMB + n*16 + am] = acc[n][r] * inv;
            }
        }
    }
}

// Batched small gates: one launch, 6 jobs max.
struct GateJob {
    const float* adj; const float* matv; const unsigned short* Et;
    const float* s; const unsigned* mm2; float* out;
    int K, Kpad, nrows, blk0;
};
struct GateJobs { GateJob j[6]; int njobs; };

__global__ __launch_bounds__(256) void k_gate_batch(GateJobs jobs)
{
    __shared__ unsigned short sh_w[64 * WPAD];
    __shared__ float sh_c[64], sh_M[64], shD[64], shZ[64];
    int b = blockIdx.x;
    int ji = 0;
    for (int q = 1; q < jobs.njobs; q++) if (b >= jobs.j[q].blk0) ji = q;
    GateJob J = jobs.j[ji];
    gate_block_mfma(J.adj, J.matv, J.Et, J.s, J.mm2, J.out, J.K, J.Kpad,
                    J.nrows, (b - J.blk0) * 64, sh_w, sh_c, sh_M, shD, shZ);
}

// ---------------------------------------------------------------------------
// FUSED item update: three V-side intra gates (MFMA, barrier-free tile loops,
// register prefetch) + the 4-way inter gate, all per 64-row block.
struct FGate {
    const float* adj; const float* matv; const unsigned short* Et;
    const unsigned* mm2; int K, Kpad, soff;
};
struct FParams { FGate g[3]; };

__global__ __launch_bounds__(256) void k_item_fused(
    FParams P, const float* __restrict__ cv, const float* __restrict__ sseg,
    const float* __restrict__ W, const float* __restrict__ bptr,
    float* __restrict__ out)
{
    __shared__ unsigned short sh_w[64 * WPAD];
    __shared__ float sh_e0[64 * E0P];
    __shared__ float shs[672];           // 650 + zero pad (Kpad overreach safe)
    __shared__ float sh_c[3][64], sh_M[3][64];
    __shared__ float shD[64], shZ[64];
    __shared__ float shWf[128];

    int tid = threadIdx.x;
    int i0  = blockIdx.x * 64;

    for (int j = tid; j < 672; j += 256) shs[j] = (j < 650) ? sseg[j] : 0.f;
    if (tid < 128) shWf[tid] = W[tid];
    if (tid < 192){
        int g = tid >> 6, r = tid & 63;
        int i = i0 + r;
        float c = (i < N_NODE) ? P.g[g].matv[i] : 0.f;
        float smin = fdekey(P.g[g].mm2[0]), smax = fdekey(P.g[g].mm2[1]);
        sh_c[g][r] = c;
        sh_M[g][r] = (c >= 0.f) ? c * smax : c * smin;
    }
    for (int f = tid; f < 64 * 32; f += 256){
        int row = f >> 5, d4 = (f & 31) * 4;
        int i = i0 + row;
        float4 v = (i < N_NODE) ? ((const float4*)(cv + (size_t)i * EMB + d4))[0]
                                : make_float4(0.f,0.f,0.f,0.f);
        ((float4*)&sh_e0[row * E0P + d4])[0] = v;
    }
    __syncthreads();    // only barrier: cross-wave staging above

    int wv = tid >> 6, lane = tid & 63;
    int half = lane >> 5, c2 = (lane & 31) * 2;
    int am = lane & 15, aq = lane >> 4;
    float bb = bptr[0];

    // e0 inter-term: dot with W (butterfly over am lanes), seed run-acc.
    float dp[4] = {0.f,0.f,0.f,0.f};
    #pragma unroll
    for (int n = 0; n < 8; n++)
        #pragma unroll
        for (int r = 0; r < 4; r++)
            dp[r] += sh_e0[(wv*16 + aq*4 + r) * E0P + n*16 + am] * shWf[n*16 + am];
    #pragma unroll
    for (int o = 1; o <= 8; o <<= 1)
        #pragma unroll
        for (int r = 0; r < 4; r++) dp[r] += __shfl_xor(dp[r], o, 64);
    float stot[4];
    #pragma unroll
    for (int r = 0; r < 4; r++) stot[r] = __expf(dp[r] + bb);
    f32x4 run[8];
    #pragma unroll
    for (int n = 0; n < 8; n++)
        #pragma unroll
        for (int r = 0; r < 4; r++)
            run[n][r] = stot[r] * sh_e0[(wv*16 + aq*4 + r) * E0P + n*16 + am];

    for (int g = 0; g < 3; g++){
        FGate G = P.g[g];
        const float* srcs = shs + G.soff;
        unsigned roff[8];
        float crow[8], Mrow[8], zacc[8], dacc[8];
        #pragma unroll
        for (int i = 0; i < 8; i++){
            int r = wv*16 + i*2 + half;
            int ir = i0 + r; if (ir >= N_NODE) ir = N_NODE - 1;
            roff[i] = (unsigned)ir * (unsigned)G.K;
            crow[i] = sh_c[g][r]; Mrow[i] = sh_M[g][r];
            zacc[i] = 0.f; dacc[i] = 0.f;
        }
        f32x4 acc[8];
        #pragma unroll
        for (int n = 0; n < 8; n++) acc[n] = (f32x4){0.f,0.f,0.f,0.f};
        int ntile = G.Kpad >> 6;

        float2 avC[8], avN[8];
        bool inbC = (c2 < G.K), inbN;
        #pragma unroll
        for (int i = 0; i < 8; i++)
            avC[i] = inbC ? *(const float2*)&G.adj[roff[i] + c2]
                          : make_float2(0.f, 0.f);

        for (int t = 0; t < ntile; t++){
            int k0 = t * 64, k0n = k0 + 64;
            inbN = (t + 1 < ntile) && (k0n + c2 < G.K);
            #pragma unroll
            for (int i = 0; i < 8; i++)
                avN[i] = inbN ? *(const float2*)&G.adj[roff[i] + k0n + c2]
                              : make_float2(0.f, 0.f);

            float2 s2 = *(const float2*)&srcs[k0 + c2];   // LDS, padded
            #pragma unroll
            for (int i = 0; i < 8; i++){
                float ex = 0.f, ey = 0.f;
                if (inbC){
                    ex = __expf(crow[i]*s2.x - Mrow[i]);
                    ey = __expf(crow[i]*s2.y - Mrow[i]);
                }
                zacc[i] += ex + ey;
                float wx = ex * avC[i].x, wy = ey * avC[i].y;
                dacc[i] += wx + wy;
                *(unsigned*)&sh_w[(wv*16 + i*2 + half) * WPAD + c2] =
                    (unsigned)f2bf(wx) | ((unsigned)f2bf(wy) << 16);
            }
            #pragma unroll
            for (int ks = 0; ks < 2; ks++){
                bf16x8 afrag = *(const bf16x8*)&sh_w[(wv*16 + am) * WPAD + ks*32 + aq*8];
                #pragma unroll
                for (int n = 0; n < 8; n++){
                    bf16x8 bfrag = *(const bf16x8*)&G.Et[(size_t)(n*16 + am) * G.Kpad + k0 + ks*32 + aq*8];
                    acc[n] = __builtin_amdgcn_mfma_f32_16x16x32_bf16(afrag, bfrag, acc[n], 0, 0, 0);
                }
            }
            inbC = inbN;
            #pragma unroll
            for (int i = 0; i < 8; i++) avC[i] = avN[i];
        }
        #pragma unroll
        for (int o = 1; o <= 16; o <<= 1)
            #pragma unroll
            for (int i = 0; i < 8; i++){
                dacc[i] += __shfl_xor(dacc[i], o, 64);
                zacc[i] += __shfl_xor(zacc[i], o, 64);
            }
        if ((lane & 31) == 0){
            #pragma unroll
            for (int i = 0; i < 8; i++){
                shD[wv*16 + i*2 + half] = dacc[i];
                shZ[wv*16 + i*2 + half] = zacc[i];
            }
        }
        // shD/shZ wave-private: no barrier.
        float inv[4];
        #pragma unroll
        for (int r = 0; r < 4; r++){
            int rl = wv*16 + aq*4 + r;
            inv[r] = 1.f / (shD[rl] + 1e-8f * shZ[rl]);
        }
        float dpg[4] = {0.f,0.f,0.f,0.f};
        #pragma unroll
        for (int n = 0; n < 8; n++)
            #pragma unroll
            for (int r = 0; r < 4; r++){
                acc[n][r] *= inv[r];
                dpg[r] += acc[n][r] * shWf[n*16 + am];
            }
        #pragma unroll
        for (int o = 1; o <= 8; o <<= 1)
            #pragma unroll
            for (int r = 0; r < 4; r++) dpg[r] += __shfl_xor(dpg[r], o, 64);
        #pragma unroll
        for (int r = 0; r < 4; r++){
            float sg = __expf(dpg[r] + bb);
            stot[r] += sg;
            #pragma unroll
            for (int n = 0; n < 8; n++) run[n][r] += sg * acc[n][r];
        }
    }
    float invs[4];
    #pragma unroll
    for (int r = 0; r < 4; r++) invs[r] = 1.f / stot[r];
    #pragma unroll
    for (int n = 0; n < 8; n++)
        #pragma unroll
        for (int r = 0; r < 4; r++){
            int i = i0 + wv*16 + aq*4 + r;
            if (i < N_NODE) out[(size_t)i * EMB + n*16 + am] = run[n][r] * invs[r];
        }
}

// ---------------------------------------------------------------------------
// transposed-side intra gate (MFMA), phase 1: 64 rows/block, chunk of CS2
// item-cols, writes partial (num[128], den, Z) per (row, chunk).
// Barrier-free tile loop + register prefetch.
__global__ __launch_bounds__(256) void k_intra_tv_mfma(
    const float* __restrict__ adj, const float* __restrict__ matv,
    const unsigned short* __restrict__ Et, const float* __restrict__ s_v,
    const unsigned* __restrict__ mm2,
    float* __restrict__ part, int baseR, int rows)
{
    __shared__ unsigned short sh_w[64 * WPAD];
    __shared__ float sh_c[64], sh_M[64], sh_s[CS2];
    int tid = threadIdx.x;
    int rb = blockIdx.x / NCH;
    int ch = blockIdx.x % NCH;
    int r0 = rb * 64;
    if (tid < 64){
        int r = r0 + tid;
        float c = (r < rows) ? matv[r] : 0.f;
        float smin = fdekey(mm2[0]), smax = fdekey(mm2[1]);
        sh_c[tid] = c;
        sh_M[tid] = (c >= 0.f) ? c * smax : c * smin;
    }
    for (int j = tid; j < CS2; j += 256){
        int gj = ch * CS2 + j;
        sh_s[j] = (gj < N_NODE) ? s_v[gj] : 0.f;
    }
    __syncthreads();    // only barrier: cross-wave staging above

    int wv = tid >> 6, lane = tid & 63;
    int half = lane >> 5, c2 = (lane & 31) * 2;
    int am = lane & 15, aq = lane >> 4;

    unsigned roff[8];
    float crow[8], Mrow[8], zacc[8], dacc[8];
    #pragma unroll
    for (int i = 0; i < 8; i++){
        int r = wv*16 + i*2 + half;
        int rr = r0 + r; if (rr >= rows) rr = rows - 1;
        roff[i] = (unsigned)rr * (unsigned)N_NODE;
        crow[i] = sh_c[r]; Mrow[i] = sh_M[r];
        zacc[i] = 0.f; dacc[i] = 0.f;
    }
    f32x4 acc[8];
    #pragma unroll
    for (int n = 0; n < 8; n++) acc[n] = (f32x4){0.f,0.f,0.f,0.f};

    float2 avC[8], avN[8];
    bool inbC = (ch * CS2 + c2) < N_NODE, inbN;
    #pragma unroll
    for (int i = 0; i < 8; i++)
        avC[i] = inbC ? *(const float2*)&adj[roff[i] + ch * CS2 + c2]
                      : make_float2(0.f, 0.f);

    for (int t = 0; t < CS2 / 64; t++){
        int k0g = ch * CS2 + t * 64;
        int k0l = t * 64;
        int k0gn = k0g + 64;
        inbN = (t + 1 < CS2 / 64) && (k0gn + c2) < N_NODE;
        #pragma unroll
        for (int i = 0; i < 8; i++)
            avN[i] = inbN ? *(const float2*)&adj[roff[i] + k0gn + c2]
                          : make_float2(0.f, 0.f);

        float2 s2 = *(const float2*)&sh_s[k0l + c2];
        #pragma unroll
        for (int i = 0; i < 8; i++){
            float ex = 0.f, ey = 0.f;
            if (inbC){
                ex = __expf(crow[i]*s2.x - Mrow[i]);
                ey = __expf(crow[i]*s2.y - Mrow[i]);
            }
            zacc[i] += ex + ey;
            float wx = ex * avC[i].x, wy = ey * avC[i].y;
            dacc[i] += wx + wy;
            *(unsigned*)&sh_w[(wv*16 + i*2 + half) * WPAD + c2] =
                (unsigned)f2bf(wx) | ((unsigned)f2bf(wy) << 16);
        }
        #pragma unroll
        for (int ks = 0; ks < 2; ks++){
            bf16x8 afrag = *(const bf16x8*)&sh_w[(wv*16 + am) * WPAD + ks*32 + aq*8];
            #pragma unroll
            for (int n = 0; n < 8; n++){
                bf16x8 bfrag = *(const bf16x8*)&Et[(size_t)(n*16 + am) * KVPAD + k0g + ks*32 + aq*8];
                acc[n] = __builtin_amdgcn_mfma_f32_16x16x32_bf16(afrag, bfrag, acc[n], 0, 0, 0);
            }
        }
        inbC = inbN;
        #pragma unroll
        for (int i = 0; i < 8; i++) avC[i] = avN[i];
    }
    #pragma unroll
    for (int o = 1; o <= 16; o <<= 1)
        #pragma unroll
        for (int i = 0; i < 8; i++){
            dacc[i] += __shfl_xor(dacc[i], o, 64);
            zacc[i] += __shfl_xor(zacc[i], o, 64);
        }
    if ((lane & 31) == 0){
        #pragma unroll
        for (int i = 0; i < 8; i++){
            int rr = r0 + wv*16 + i*2 + half;
            if (rr < rows){
                float* d2 = part + ((size_t)(baseR + rr) * NCH + ch) * RSTRIDE;
                d2[128] = dacc[i]; d2[129] = zacc[i];
            }
        }
    }
    #pragma unroll
    for (int n = 0; n < 8; n++){
        #pragma unroll
        for (int r = 0; r < 4; r++){
            int rl = wv*16 + aq*4 + r;
            int rr = r0 + rl;
            if (rr < rows){
                float* d2 = part + ((size_t)(baseR + rr) * NCH + ch) * RSTRIDE;
                d2[n*16 + am] = acc[n][r];
            }
        }
    }
}

// ---------------------------------------------------------------------------
// Batched phase-2: reduce big-gate partials over NCH chunks + 4-way inter
// gate from precomputed small-gate buffers. One 128-thr block per row.
struct RIJob {
    const float* e0; float* out; const float* gA; const float* gB;
    const float* W; const float* b; int baseR; int nrows; int row0;
};
struct RIJobs { RIJob j[3]; int njobs; };

__global__ __launch_bounds__(128) void k_reduce_inter(
    RIJobs jobs, const float* __restrict__ part)
{
    __shared__ float sh[4][EMB];
    __shared__ float shW[EMB];
    int b = blockIdx.x;
    int ji = 0;
    for (int q = 1; q < jobs.njobs; q++) if (b >= jobs.j[q].row0) ji = q;
    RIJob J = jobs.j[ji];
    int r = b - J.row0;
    int d = threadIdx.x;
    float num = 0.f, den = 0.f, Z = 0.f;
    for (int c = 0; c < NCH; c++){
        const float* p = part + ((size_t)(J.baseR + r) * NCH + c) * RSTRIDE;
        num += p[d]; den += p[128]; Z += p[129];
    }
    sh[1][d] = num / (den + 1e-8f * Z);
    sh[0][d] = J.e0[(size_t)r * EMB + d];
    sh[2][d] = J.gA[(size_t)r * EMB + d];
    sh[3][d] = J.gB[(size_t)r * EMB + d];
    shW[d] = J.W[d];
    __syncthreads();
    float dots[4];
    #pragma unroll
    for (int g = 0; g < 4; g++){
        float acc = 0.f;
        for (int k = 0; k < EMB; k++) acc += sh[g][k] * shW[k];
        dots[g] = acc;
    }
    float bb = J.b[0];
    float s0 = __expf(dots[0] + bb), s1 = __expf(dots[1] + bb);
    float s2 = __expf(dots[2] + bb), s3 = __expf(dots[3] + bb);
    float inv = 1.f / (s0 + s1 + s2 + s3);
    J.out[(size_t)r * EMB + d] =
        (s0*sh[0][d] + s1*sh[1][d] + s2*sh[2][d] + s3*sh[3][d]) * inv;
}

// ---------------------------------------------------------------------------
extern "C" void kernel_launch(void* const* d_in, const int* in_sizes, int n_in,
                              void* d_out, int out_size, void* d_ws, size_t ws_size,
                              hipStream_t stream)
{
    const int*   adj_idx  = (const int*)d_in[0];
    const float* adj_val  = (const float*)d_in[1];
    const float* a_pv   = (const float*)d_in[2];
    const float* a_vp   = (const float*)d_in[3];
    const float* a_pcb  = (const float*)d_in[4];
    const float* a_cbp  = (const float*)d_in[5];
    const float* a_cbv  = (const float*)d_in[6];
    const float* a_vcb  = (const float*)d_in[7];
    const float* a_pcm  = (const float*)d_in[8];
    const float* a_cmp  = (const float*)d_in[9];
    const float* a_cmv  = (const float*)d_in[10];
    const float* a_vcm  = (const float*)d_in[11];
    const float* a_cbcm = (const float*)d_in[12];
    const float* a_cmcb = (const float*)d_in[13];
    const float* in_item = (const float*)d_in[14];
    const float* in_pri  = (const float*)d_in[15];
    const float* in_cb   = (const float*)d_in[16];
    const float* in_cm   = (const float*)d_in[17];
    const float* m_vp  = (const float*)d_in[18];
    const float* m_vcb = (const float*)d_in[19];
    const float* m_vcm = (const float*)d_in[20];
    const float* m_pv  = (const float*)d_in[21];
    const float* m_pcb = (const float*)d_in[22];
    const float* m_pcm = (const float*)d_in[23];
    const float* m_cbp = (const float*)d_in[24];
    const float* m_cbv = (const float*)d_in[25];
    const float* m_cbcm= (const float*)d_in[26];
    const float* m_cmp = (const float*)d_in[27];
    const float* m_cmv = (const float*)d_in[28];
    const float* m_cmcb= (const float*)d_in[29];
    const float* Wi = (const float*)d_in[30]; const float* bi = (const float*)d_in[31];
    const float* Wp = (const float*)d_in[32]; const float* bp = (const float*)d_in[33];
    const float* Wcb= (const float*)d_in[34]; const float* bcb= (const float*)d_in[35];
    const float* Wcm= (const float*)d_in[36]; const float* bcm= (const float*)d_in[37];

    float* ws = (float*)d_ws;
    size_t off = 0;
    auto alloc = [&](size_t n){ float* p = ws + off; off += (n + 63) & ~(size_t)63; return p; };
    float* buf_item = alloc((size_t)N_NODE * EMB);
    float* buf_pri  = alloc((size_t)N_PRICE * EMB);
    float* buf_cb   = alloc((size_t)N_CB * EMB);
    float* buf_cm   = alloc((size_t)N_CM * EMB);
    float* s_all    = alloc(N_NODE + N_PRICE + N_CB + N_CM);
    unsigned* mm    = (unsigned*)alloc(64);
    float* g1 = alloc((size_t)N_NODE * EMB);
    float* g3 = alloc((size_t)N_NODE * EMB);
    float* part = g1;                       // 650*64*132 = 5.49M floats, alias g1
    unsigned short* et_v = (unsigned short*)g3;  // 13.6 MB, alias g3
    int*   counts = (int*)alloc(N_NODE + 64);
    int*   offs   = (int*)alloc(N_NODE + 64);
    int*   cursor = (int*)alloc(N_NODE + 64);
    int*   scol   = (int*)alloc(NNZE);
    float* sval   = alloc(NNZE);
    unsigned short* et_p  = (unsigned short*)alloc(EMB * 128 / 2);
    unsigned short* et_cb = (unsigned short*)alloc(EMB * 64 / 2);
    unsigned short* et_cm = (unsigned short*)alloc(EMB * 512 / 2);
    float* g_pcb  = alloc((size_t)N_PRICE * EMB);
    float* g_pcm  = alloc((size_t)N_PRICE * EMB);
    float* g_cbp  = alloc((size_t)N_CB * EMB);
    float* g_cbcm = alloc((size_t)N_CB * EMB);
    float* g_cmp  = alloc((size_t)N_CM * EMB);
    float* g_cmcb = alloc((size_t)N_CM * EMB);

    float* out_item = (float*)d_out;
    float* out_pri  = (float*)d_out + (size_t)N_NODE * EMB;

    const float* s_v  = s_all;
    const float* s_p  = s_all + N_NODE;
    const float* s_cb = s_all + N_NODE + N_PRICE;
    const float* s_cm = s_all + N_NODE + N_PRICE + N_CB;

    const int totr = N_NODE + N_PRICE + N_CB + N_CM;

    // ---- CSR build (once; adjacency is layer-invariant) ----
    hipMemsetAsync(counts, 0, N_NODE * sizeof(int), stream);
    k_hist<<<(NNZE + 255)/256, 256, 0, stream>>>(adj_idx, counts);
    k_scan<<<1, SCAN_T, 0, stream>>>(counts, offs, cursor);
    k_scatter<<<(NNZE + 255)/256, 256, 0, stream>>>(adj_idx, adj_idx + NNZE,
                                                    adj_val, cursor, scol, sval);

    for (int layer = 0; layer < 2; layer++){
        const float* cv  = layer ? buf_item : in_item;
        const float* cp  = layer ? buf_pri  : in_pri;
        const float* ccb = layer ? buf_cb   : in_cb;
        const float* ccm = layer ? buf_cm   : in_cm;
        float* ov = layer ? out_item : buf_item;
        float* op = layer ? out_pri  : buf_pri;

        k_rowsum<<<(totr + 3)/4, 256, 0, stream>>>(cv, cp, ccb, ccm, s_all, mm);
        k_minmax<<<(totr + 255)/256, 256, 0, stream>>>(s_all, mm);

        // bf16 transposed operands for p/cb/cm-source gates (tiled transpose)
        k_cast_et_t<<<dim3(2, 2), 256, 0, stream>>>(cp,  et_p,  N_PRICE, 128);
        k_cast_et_t<<<dim3(1, 2), 256, 0, stream>>>(ccb, et_cb, N_CB,    64);
        k_cast_et_t<<<dim3(8, 2), 256, 0, stream>>>(ccm, et_cm, N_CM,    512);

        // batched small gates (MFMA)
        GateJobs gj{};
        int nb = 0, nj = 0;
        auto addjob = [&](const float* adj_, const float* matv_,
                          const unsigned short* Et_, const float* s_,
                          const unsigned* mm2_, float* out_,
                          int K_, int Kpad_, int nrows_){
            gj.j[nj] = GateJob{adj_, matv_, Et_, s_, mm2_, out_,
                               K_, Kpad_, nrows_, nb};
            nb += (nrows_ + 63) / 64; nj++;
        };
        addjob(a_pcb, m_pcb, et_cb, s_cb, mm+4, g_pcb, N_CB,    64, N_PRICE);
        addjob(a_pcm, m_pcm, et_cm, s_cm, mm+6, g_pcm, N_CM,   512, N_PRICE);
        if (layer == 0){
            addjob(a_cbp,  m_cbp,  et_p,  s_p,  mm+2, g_cbp,  N_PRICE, 128, N_CB);
            addjob(a_cbcm, m_cbcm, et_cm, s_cm, mm+6, g_cbcm, N_CM,   512, N_CB);
            addjob(a_cmp,  m_cmp,  et_p,  s_p,  mm+2, g_cmp,  N_PRICE, 128, N_CM);
            addjob(a_cmcb, m_cmcb, et_cb, s_cb, mm+4, g_cmcb, N_CB,    64, N_CM);
        }
        gj.njobs = nj;
        k_gate_batch<<<nb, 256, 0, stream>>>(gj);

        // fused item update (3 intra gates + inter gate)
        FParams fp{};
        fp.g[0] = FGate{a_vp,  m_vp,  et_p,  mm+2, N_PRICE, 128, 0};
        fp.g[1] = FGate{a_vcb, m_vcb, et_cb, mm+4, N_CB,    64,  100};
        fp.g[2] = FGate{a_vcm, m_vcm, et_cm, mm+6, N_CM,    512, 150};
        k_item_fused<<<(N_NODE + 63)/64, 256, 0, stream>>>(
            fp, cv, s_all + N_NODE, Wi, bi, ov);

        k_spmm_csr<<<(N_NODE*64 + 255)/256, 256, 0, stream>>>(offs, scol, sval, cv, ov);

        // item-side bf16 transposed operand (aliases g3, now dead)
        k_cast_et_t<<<dim3(KVPAD/64, 2), 256, 0, stream>>>(cv, et_v, N_NODE, KVPAD);

        k_intra_tv_mfma<<<((N_PRICE + 63)/64) * NCH, 256, 0, stream>>>(
            a_pv, m_pv, et_v, s_v, mm + 0, part, 0, N_PRICE);
        if (layer == 0){
            k_intra_tv_mfma<<<((N_CB + 63)/64) * NCH, 256, 0, stream>>>(
                a_cbv, m_cbv, et_v, s_v, mm + 0, part, N_PRICE, N_CB);
            k_intra_tv_mfma<<<((N_CM + 63)/64) * NCH, 256, 0, stream>>>(
                a_cmv, m_cmv, et_v, s_v, mm + 0, part, N_PRICE + N_CB, N_CM);
        }

        // batched phase-2 reduce + inter
        RIJobs rj{};
        rj.j[0] = RIJob{cp, op, g_pcb, g_pcm, Wp, bp, 0, N_PRICE, 0};
        int nrows_tot = N_PRICE;
        int njr = 1;
        if (layer == 0){
            rj.j[1] = RIJob{ccb, buf_cb, g_cbp, g_cbcm, Wcb, bcb,
                            N_PRICE, N_CB, nrows_tot};
            nrows_tot += N_CB; njr++;
            rj.j[2] = RIJob{ccm, buf_cm, g_cmp, g_cmcb, Wcm, bcm,
                            N_PRICE + N_CB, N_CM, nrows_tot};
            nrows_tot += N_CM; njr++;
        }
        rj.njobs = njr;
        k_reduce_inter<<<nrows_tot, 128, 0, stream>>>(rj, part);
    }
    (void)in_sizes; (void)n_in; (void)out_size; (void)ws_size;
}

// Round 3
// 1216.195 us; speedup vs baseline: 1.3599x; 1.0466x over previous
//
#include <hip/hip_runtime.h>

#define N_NODE 50000
#define N_PRICE 100
#define N_CB 50
#define N_CM 500
#define EMB 128
#define NNZE 1000000
#define NCH 64         /* tv chunks */
#define CS2 832        /* 13 tiles of 64 cols; 64*832 = 53248 >= 50000 */
#define KVPAD 53248
#define RSTRIDE 132    /* 128 num + den + Z + pad */
#define SCAN_T 1024
#define WPAD 72        /* sh_w row stride in bf16 (64 + 8 pad) */
#define E0P 132        /* sh_e0 row stride (fp32), 16B-aligned rows */

typedef __attribute__((ext_vector_type(8))) short bf16x8;
typedef __attribute__((ext_vector_type(4))) float f32x4;

// ---- monotone float<->uint keys for atomic min/max on floats ----
__device__ inline unsigned fkey(float f){
    unsigned b = __float_as_uint(f);
    return (b & 0x80000000u) ? ~b : (b | 0x80000000u);
}
__device__ inline float fdekey(unsigned k){
    unsigned b = (k & 0x80000000u) ? (k & 0x7fffffffu) : ~k;
    return __uint_as_float(b);
}
// fp32 -> bf16 (RNE), bit form
__device__ inline unsigned short f2bf(float f){
    unsigned u = __float_as_uint(f);
    u += 0x7FFFu + ((u >> 16) & 1u);
    return (unsigned short)(u >> 16);
}

// ---------------------------------------------------------------------------
__global__ __launch_bounds__(256) void k_rowsum(
    const float* __restrict__ e_v, const float* __restrict__ e_p,
    const float* __restrict__ e_cb, const float* __restrict__ e_cm,
    float* __restrict__ s_all, unsigned* __restrict__ mm)
{
    if (blockIdx.x == 0 && threadIdx.x < 8)
        mm[threadIdx.x] = (threadIdx.x & 1) ? 0u : 0xFFFFFFFFu;
    int wid  = (blockIdx.x * 256 + threadIdx.x) >> 6;
    int lane = threadIdx.x & 63;
    const int NT = N_NODE + N_PRICE + N_CB + N_CM;
    if (wid >= NT) return;
    const float* src; int lr;
    if (wid < N_NODE)                { src = e_v;  lr = wid; }
    else if (wid < N_NODE+N_PRICE)   { src = e_p;  lr = wid - N_NODE; }
    else if (wid < N_NODE+N_PRICE+N_CB){ src = e_cb; lr = wid - N_NODE - N_PRICE; }
    else                             { src = e_cm; lr = wid - N_NODE - N_PRICE - N_CB; }
    float2 v = ((const float2*)(src + (size_t)lr * EMB))[lane];
    float sum = v.x + v.y;
    #pragma unroll
    for (int o = 32; o > 0; o >>= 1) sum += __shfl_down(sum, o, 64);
    if (lane == 0) s_all[wid] = sum;
}

__global__ __launch_bounds__(256) void k_minmax(
    const float* __restrict__ s_all, unsigned* __restrict__ mm)
{
    __shared__ unsigned smin[4], smax[4];
    int t = threadIdx.x;
    if (t < 4){ smin[t] = 0xFFFFFFFFu; smax[t] = 0u; }
    __syncthreads();
    int gid = blockIdx.x * 256 + t;
    const int NT = N_NODE + N_PRICE + N_CB + N_CM;
    if (gid < NT){
        int ty = (gid < N_NODE) ? 0 :
                 (gid < N_NODE+N_PRICE) ? 1 :
                 (gid < N_NODE+N_PRICE+N_CB) ? 2 : 3;
        unsigned k = fkey(s_all[gid]);
        atomicMin(&smin[ty], k);
        atomicMax(&smax[ty], k);
    }
    __syncthreads();
    if (t < 4){
        if (smin[t] != 0xFFFFFFFFu) atomicMin(&mm[2*t],   smin[t]);
        if (smax[t] != 0u)          atomicMax(&mm[2*t+1], smax[t]);
    }
}

// ---------------------------------------------------------------------------
// CSR build: histogram -> scan -> scatter. Built ONCE per call, used twice.
__global__ __launch_bounds__(256) void k_hist(
    const int* __restrict__ rows, int* __restrict__ counts)
{
    int i = blockIdx.x * 256 + threadIdx.x;
    if (i < NNZE) atomicAdd(&counts[rows[i]], 1);
}

__global__ __launch_bounds__(SCAN_T) void k_scan(
    const int* __restrict__ counts, int* __restrict__ offs, int* __restrict__ cursor)
{
    __shared__ int part[SCAN_T];
    int t = threadIdx.x;
    const int CHUNK = (N_NODE + SCAN_T - 1) / SCAN_T;
    int base = t * CHUNK;
    int s = 0;
    for (int i = 0; i < CHUNK; i++){
        int idx = base + i;
        if (idx < N_NODE) s += counts[idx];
    }
    part[t] = s;
    __syncthreads();
    for (int o = 1; o < SCAN_T; o <<= 1){
        int u = (t >= o) ? part[t - o] : 0;
        __syncthreads();
        part[t] += u;
        __syncthreads();
    }
    int run = part[t] - s;
    for (int i = 0; i < CHUNK; i++){
        int idx = base + i;
        if (idx < N_NODE){
            offs[idx] = run; cursor[idx] = run;
            run += counts[idx];
        }
    }
    if (t == SCAN_T - 1) offs[N_NODE] = run;
}

__global__ __launch_bounds__(256) void k_scatter(
    const int* __restrict__ rows, const int* __restrict__ cols,
    const float* __restrict__ vals, int* __restrict__ cursor,
    int* __restrict__ scol, float* __restrict__ sval)
{
    int i = blockIdx.x * 256 + threadIdx.x;
    if (i < NNZE){
        int r = rows[i];
        int p = atomicAdd(&cursor[r], 1);
        scol[p] = cols[i];
        sval[p] = vals[i];
    }
}

// CSR spmm: one wave per row; lanes cooperatively load nnz, broadcast via shfl.
__global__ __launch_bounds__(256) void k_spmm_csr(
    const int* __restrict__ offs, const int* __restrict__ scol,
    const float* __restrict__ sval, const float* __restrict__ emb,
    float* __restrict__ out)
{
    int row  = (blockIdx.x * 256 + threadIdx.x) >> 6;
    int lane = threadIdx.x & 63;
    if (row >= N_NODE) return;
    int s = offs[row], e = offs[row + 1];
    float2 acc = make_float2(0.f, 0.f);
    for (int base = s; base < e; base += 64){
        int n = base + lane;
        int   cl = (n < e) ? scol[n] : 0;
        float vl = (n < e) ? sval[n] : 0.f;
        int m = e - base; if (m > 64) m = 64;
        for (int j = 0; j < m; j++){
            int   c = __shfl(cl, j, 64);
            float v = __shfl(vl, j, 64);
            float2 em = *(const float2*)(emb + (size_t)c * EMB + lane * 2);
            acc.x += v * em.x; acc.y += v * em.y;
        }
    }
    float* dst = out + (size_t)row * EMB + lane * 2;
    float2 o = *(float2*)dst;
    o.x += acc.x; o.y += acc.y;
    *(float2*)dst = o;
}

// ---------------------------------------------------------------------------
// Tiled transpose-cast: emb [K][EMB] fp32 -> Et [EMB][Kpad] bf16.
__global__ __launch_bounds__(256) void k_cast_et_t(
    const float* __restrict__ emb, unsigned short* __restrict__ Et,
    int K, int Kpad)
{
    __shared__ unsigned short tl[64][72];
    int k0 = blockIdx.x * 64, d0 = blockIdx.y * 64;
    int t = threadIdx.x;
    int r = t >> 2, cb = (t & 3) * 16;
    const float* src = emb + (size_t)(k0 + r) * EMB + d0 + cb;
    bool rv = (k0 + r) < K;
    #pragma unroll
    for (int q = 0; q < 4; q++){
        float4 v = rv ? ((const float4*)src)[q] : make_float4(0.f,0.f,0.f,0.f);
        tl[r][cb + q*4 + 0] = f2bf(v.x);
        tl[r][cb + q*4 + 1] = f2bf(v.y);
        tl[r][cb + q*4 + 2] = f2bf(v.z);
        tl[r][cb + q*4 + 3] = f2bf(v.w);
    }
    __syncthreads();
    unsigned short h[16];
    #pragma unroll
    for (int j = 0; j < 16; j++) h[j] = tl[cb + j][r];
    uint4* dst = (uint4*)(Et + (size_t)(d0 + r) * Kpad + k0 + cb);
    dst[0] = make_uint4(((unsigned)h[1]<<16)|h[0], ((unsigned)h[3]<<16)|h[2],
                        ((unsigned)h[5]<<16)|h[4], ((unsigned)h[7]<<16)|h[6]);
    dst[1] = make_uint4(((unsigned)h[9]<<16)|h[8], ((unsigned)h[11]<<16)|h[10],
                        ((unsigned)h[13]<<16)|h[12],((unsigned)h[15]<<16)|h[14]);
}

// ---------------------------------------------------------------------------
// Shared MFMA gate block body. Barrier-free tile loop; register-resident
// pipeline: Et B-frags for tile t loaded into bfr[16] FIRST, then next-tile
// adj prefetch, then exp/pack/ds_write, then MFMAs. vmcnt is in-order, so
// the MFMA waits leave the prefetch loads in flight (vmcnt(8), never 0).
// Requires the relaxed register budget from __launch_bounds__(256,2).
__device__ inline void gate_block_mfma(
    const float* __restrict__ adj, const float* __restrict__ matv,
    const unsigned short* __restrict__ Et, const float* __restrict__ s_src,
    const unsigned* __restrict__ mm2, float* __restrict__ out,
    int K, int Kpad, int nrows, int i0,
    unsigned short* sh_w, float* sh_c, float* sh_M, float* shD, float* shZ)
{
    int tid = threadIdx.x;
    if (tid < 64){
        int i = i0 + tid;
        float c = (i < nrows) ? matv[i] : 0.f;
        float smin = fdekey(mm2[0]), smax = fdekey(mm2[1]);
        sh_c[tid] = c;
        sh_M[tid] = (c >= 0.f) ? c * smax : c * smin;
    }
    __syncthreads();    // only barrier: sh_c/sh_M staging is cross-wave

    int wv = tid >> 6, lane = tid & 63;
    int half = lane >> 5, c2 = (lane & 31) * 2;
    int am = lane & 15, aq = lane >> 4;

    unsigned roff[8];
    float crow[8], Mrow[8], zacc[8], dacc[8];
    #pragma unroll
    for (int i = 0; i < 8; i++){
        int r = wv*16 + i*2 + half;
        int ir = i0 + r; if (ir >= nrows) ir = nrows - 1;
        roff[i] = (unsigned)ir * (unsigned)K;
        crow[i] = sh_c[r]; Mrow[i] = sh_M[r];
        zacc[i] = 0.f; dacc[i] = 0.f;
    }
    f32x4 acc[8];
    #pragma unroll
    for (int n = 0; n < 8; n++) acc[n] = (f32x4){0.f,0.f,0.f,0.f};

    int ntile = Kpad / 64;
    float2 avC[8], avN[8], s2C, s2N;
    bool inbC = (c2 < K), inbN;
    s2C = inbC ? *(const float2*)&s_src[c2] : make_float2(0.f, 0.f);
    #pragma unroll
    for (int i = 0; i < 8; i++)
        avC[i] = inbC ? *(const float2*)&adj[roff[i] + c2] : make_float2(0.f, 0.f);

    for (int t = 0; t < ntile; t++){
        int k0 = t * 64, k0n = k0 + 64;
        // 1) Et B-fragments for THIS tile -> registers (issued first so the
        //    MFMA wait doesn't drain the prefetch below)
        bf16x8 bfr[16];
        #pragma unroll
        for (int ks = 0; ks < 2; ks++)
            #pragma unroll
            for (int n = 0; n < 8; n++)
                bfr[ks*8+n] = *(const bf16x8*)&Et[(size_t)(n*16 + am) * Kpad + k0 + ks*32 + aq*8];
        // 2) next-tile adjacency prefetch
        inbN = (t + 1 < ntile) && (k0n + c2 < K);
        s2N = inbN ? *(const float2*)&s_src[k0n + c2] : make_float2(0.f, 0.f);
        #pragma unroll
        for (int i = 0; i < 8; i++)
            avN[i] = inbN ? *(const float2*)&adj[roff[i] + k0n + c2]
                          : make_float2(0.f, 0.f);
        // 3) exp / weight / pack (uses avC, loaded one tile ago)
        #pragma unroll
        for (int i = 0; i < 8; i++){
            float ex = 0.f, ey = 0.f;
            if (inbC){
                ex = __expf(crow[i]*s2C.x - Mrow[i]);
                ey = __expf(crow[i]*s2C.y - Mrow[i]);
            }
            zacc[i] += ex + ey;
            float wx = ex * avC[i].x, wy = ey * avC[i].y;
            dacc[i] += wx + wy;
            *(unsigned*)&sh_w[(wv*16 + i*2 + half) * WPAD + c2] =
                (unsigned)f2bf(wx) | ((unsigned)f2bf(wy) << 16);
        }
        // 4) MFMA from registers + wave-private LDS
        #pragma unroll
        for (int ks = 0; ks < 2; ks++){
            bf16x8 afrag = *(const bf16x8*)&sh_w[(wv*16 + am) * WPAD + ks*32 + aq*8];
            #pragma unroll
            for (int n = 0; n < 8; n++)
                acc[n] = __builtin_amdgcn_mfma_f32_16x16x32_bf16(afrag, bfr[ks*8+n], acc[n], 0, 0, 0);
        }
        inbC = inbN; s2C = s2N;
        #pragma unroll
        for (int i = 0; i < 8; i++) avC[i] = avN[i];
    }
    #pragma unroll
    for (int o = 1; o <= 16; o <<= 1)
        #pragma unroll
        for (int i = 0; i < 8; i++){
            dacc[i] += __shfl_xor(dacc[i], o, 64);
            zacc[i] += __shfl_xor(zacc[i], o, 64);
        }
    if ((lane & 31) == 0){
        #pragma unroll
        for (int i = 0; i < 8; i++){
            shD[wv*16 + i*2 + half] = dacc[i];
            shZ[wv*16 + i*2 + half] = zacc[i];
        }
    }
    // shD/shZ rows are wave-private: no barrier, in-wave lgkm suffices.
    #pragma unroll
    for (int n = 0; n < 8; n++){
        #pragma unroll
        for (int r = 0; r < 4; r++){
            int rl = wv*16 + aq*4 + r;
            int i  = i0 + rl;
            if (i < nrows){
                float inv = 1.f / (shD[rl] + 1e-8f * shZ[rl]);
                out[(size_t)i * EMB + n*16 + am] = acc[n][r] * inv;
            }
        }
    }
}

// Batched small gates: one launch, 6 jobs max.
struct GateJob {
    const float* adj; const float* matv; const unsigned short* Et;
    const float* s; const unsigned* mm2; float* out;
    int K, Kpad, nrows, blk0;
};
struct GateJobs { GateJob j[6]; int njobs; };

__global__ __launch_bounds__(256, 2) void k_gate_batch(GateJobs jobs)
{
    __shared__ unsigned short sh_w[64 * WPAD];
    __shared__ float sh_c[64], sh_M[64], shD[64], shZ[64];
    int b = blockIdx.x;
    int ji = 0;
    for (int q = 1; q < jobs.njobs; q++) if (b >= jobs.j[q].blk0) ji = q;
    GateJob J = jobs.j[ji];
    gate_block_mfma(J.adj, J.matv, J.Et, J.s, J.mm2, J.out, J.K, J.Kpad,
                    J.nrows, (b - J.blk0) * 64, sh_w, sh_c, sh_M, shD, shZ);
}

// ---------------------------------------------------------------------------
// FUSED item update: three V-side intra gates (register-pipelined MFMA) +
// the 4-way inter gate, all per 64-row block.
struct FGate {
    const float* adj; const float* matv; const unsigned short* Et;
    const unsigned* mm2; int K, Kpad, soff;
};
struct FParams { FGate g[3]; };

__global__ __launch_bounds__(256, 2) void k_item_fused(
    FParams P, const float* __restrict__ cv, const float* __restrict__ sseg,
    const float* __restrict__ W, const float* __restrict__ bptr,
    float* __restrict__ out)
{
    __shared__ unsigned short sh_w[64 * WPAD];
    __shared__ float sh_e0[64 * E0P];
    __shared__ float shs[672];           // 650 + zero pad (Kpad overreach safe)
    __shared__ float sh_c[3][64], sh_M[3][64];
    __shared__ float shD[64], shZ[64];
    __shared__ float shWf[128];

    int tid = threadIdx.x;
    int i0  = blockIdx.x * 64;

    for (int j = tid; j < 672; j += 256) shs[j] = (j < 650) ? sseg[j] : 0.f;
    if (tid < 128) shWf[tid] = W[tid];
    if (tid < 192){
        int g = tid >> 6, r = tid & 63;
        int i = i0 + r;
        float c = (i < N_NODE) ? P.g[g].matv[i] : 0.f;
        float smin = fdekey(P.g[g].mm2[0]), smax = fdekey(P.g[g].mm2[1]);
        sh_c[g][r] = c;
        sh_M[g][r] = (c >= 0.f) ? c * smax : c * smin;
    }
    for (int f = tid; f < 64 * 32; f += 256){
        int row = f >> 5, d4 = (f & 31) * 4;
        int i = i0 + row;
        float4 v = (i < N_NODE) ? ((const float4*)(cv + (size_t)i * EMB + d4))[0]
                                : make_float4(0.f,0.f,0.f,0.f);
        ((float4*)&sh_e0[row * E0P + d4])[0] = v;
    }
    __syncthreads();    // only barrier: cross-wave staging above

    int wv = tid >> 6, lane = tid & 63;
    int half = lane >> 5, c2 = (lane & 31) * 2;
    int am = lane & 15, aq = lane >> 4;
    float bb = bptr[0];

    // e0 inter-term: dot with W (butterfly over am lanes), seed run-acc.
    float dp[4] = {0.f,0.f,0.f,0.f};
    #pragma unroll
    for (int n = 0; n < 8; n++)
        #pragma unroll
        for (int r = 0; r < 4; r++)
            dp[r] += sh_e0[(wv*16 + aq*4 + r) * E0P + n*16 + am] * shWf[n*16 + am];
    #pragma unroll
    for (int o = 1; o <= 8; o <<= 1)
        #pragma unroll
        for (int r = 0; r < 4; r++) dp[r] += __shfl_xor(dp[r], o, 64);
    float stot[4];
    #pragma unroll
    for (int r = 0; r < 4; r++) stot[r] = __expf(dp[r] + bb);
    f32x4 run[8];
    #pragma unroll
    for (int n = 0; n < 8; n++)
        #pragma unroll
        for (int r = 0; r < 4; r++)
            run[n][r] = stot[r] * sh_e0[(wv*16 + aq*4 + r) * E0P + n*16 + am];

    for (int g = 0; g < 3; g++){
        FGate G = P.g[g];
        const float* srcs = shs + G.soff;
        unsigned roff[8];
        float crow[8], Mrow[8], zacc[8], dacc[8];
        #pragma unroll
        for (int i = 0; i < 8; i++){
            int r = wv*16 + i*2 + half;
            int ir = i0 + r; if (ir >= N_NODE) ir = N_NODE - 1;
            roff[i] = (unsigned)ir * (unsigned)G.K;
            crow[i] = sh_c[g][r]; Mrow[i] = sh_M[g][r];
            zacc[i] = 0.f; dacc[i] = 0.f;
        }
        f32x4 acc[8];
        #pragma unroll
        for (int n = 0; n < 8; n++) acc[n] = (f32x4){0.f,0.f,0.f,0.f};
        int ntile = G.Kpad >> 6;

        float2 avC[8], avN[8];
        bool inbC = (c2 < G.K), inbN;
        #pragma unroll
        for (int i = 0; i < 8; i++)
            avC[i] = inbC ? *(const float2*)&G.adj[roff[i] + c2]
                          : make_float2(0.f, 0.f);

        for (int t = 0; t < ntile; t++){
            int k0 = t * 64, k0n = k0 + 64;
            // 1) Et B-frags for this tile -> registers (before prefetch!)
            bf16x8 bfr[16];
            #pragma unroll
            for (int ks = 0; ks < 2; ks++)
                #pragma unroll
                for (int n = 0; n < 8; n++)
                    bfr[ks*8+n] = *(const bf16x8*)&G.Et[(size_t)(n*16 + am) * G.Kpad + k0 + ks*32 + aq*8];
            // 2) next-tile adjacency prefetch
            inbN = (t + 1 < ntile) && (k0n + c2 < G.K);
            #pragma unroll
            for (int i = 0; i < 8; i++)
                avN[i] = inbN ? *(const float2*)&G.adj[roff[i] + k0n + c2]
                              : make_float2(0.f, 0.f);
            // 3) exp / weight / pack (uses avC)
            float2 s2 = *(const float2*)&srcs[k0 + c2];   // LDS, padded
            #pragma unroll
            for (int i = 0; i < 8; i++){
                float ex = 0.f, ey = 0.f;
                if (inbC){
                    ex = __expf(crow[i]*s2.x - Mrow[i]);
                    ey = __expf(crow[i]*s2.y - Mrow[i]);
                }
                zacc[i] += ex + ey;
                float wx = ex * avC[i].x, wy = ey * avC[i].y;
                dacc[i] += wx + wy;
                *(unsigned*)&sh_w[(wv*16 + i*2 + half) * WPAD + c2] =
                    (unsigned)f2bf(wx) | ((unsigned)f2bf(wy) << 16);
            }
            // 4) MFMA from registers + wave-private LDS
            #pragma unroll
            for (int ks = 0; ks < 2; ks++){
                bf16x8 afrag = *(const bf16x8*)&sh_w[(wv*16 + am) * WPAD + ks*32 + aq*8];
                #pragma unroll
                for (int n = 0; n < 8; n++)
                    acc[n] = __builtin_amdgcn_mfma_f32_16x16x32_bf16(afrag, bfr[ks*8+n], acc[n], 0, 0, 0);
            }
            inbC = inbN;
            #pragma unroll
            for (int i = 0; i < 8; i++) avC[i] = avN[i];
        }
        #pragma unroll
        for (int o = 1; o <= 16; o <<= 1)
            #pragma unroll
            for (int i = 0; i < 8; i++){
                dacc[i] += __shfl_xor(dacc[i], o, 64);
                zacc[i] += __shfl_xor(zacc[i], o, 64);
            }
        if ((lane & 31) == 0){
            #pragma unroll
            for (int i = 0; i < 8; i++){
                shD[wv*16 + i*2 + half] = dacc[i];
                shZ[wv*16 + i*2 + half] = zacc[i];
            }
        }
        // shD/shZ wave-private: no barrier.
        float inv[4];
        #pragma unroll
        for (int r = 0; r < 4; r++){
            int rl = wv*16 + aq*4 + r;
            inv[r] = 1.f / (shD[rl] + 1e-8f * shZ[rl]);
        }
        float dpg[4] = {0.f,0.f,0.f,0.f};
        #pragma unroll
        for (int n = 0; n < 8; n++)
            #pragma unroll
            for (int r = 0; r < 4; r++){
                acc[n][r] *= inv[r];
                dpg[r] += acc[n][r] * shWf[n*16 + am];
            }
        #pragma unroll
        for (int o = 1; o <= 8; o <<= 1)
            #pragma unroll
            for (int r = 0; r < 4; r++) dpg[r] += __shfl_xor(dpg[r], o, 64);
        #pragma unroll
        for (int r = 0; r < 4; r++){
            float sg = __expf(dpg[r] + bb);
            stot[r] += sg;
            #pragma unroll
            for (int n = 0; n < 8; n++) run[n][r] += sg * acc[n][r];
        }
    }
    float invs[4];
    #pragma unroll
    for (int r = 0; r < 4; r++) invs[r] = 1.f / stot[r];
    #pragma unroll
    for (int n = 0; n < 8; n++)
        #pragma unroll
        for (int r = 0; r < 4; r++){
            int i = i0 + wv*16 + aq*4 + r;
            if (i < N_NODE) out[(size_t)i * EMB + n*16 + am] = run[n][r] * invs[r];
        }
}

// ---------------------------------------------------------------------------
// transposed-side intra gate (MFMA), phase 1: 64 rows/block, chunk of CS2
// item-cols, writes partial (num[128], den, Z) per (row, chunk).
// Register-pipelined like gate_block_mfma.
__global__ __launch_bounds__(256, 2) void k_intra_tv_mfma(
    const float* __restrict__ adj, const float* __restrict__ matv,
    const unsigned short* __restrict__ Et, const float* __restrict__ s_v,
    const unsigned* __restrict__ mm2,
    float* __restrict__ part, int baseR, int rows)
{
    __shared__ unsigned short sh_w[64 * WPAD];
    __shared__ float sh_c[64], sh_M[64], sh_s[CS2];
    int tid = threadIdx.x;
    int rb = blockIdx.x / NCH;
    int ch = blockIdx.x % NCH;
    int r0 = rb * 64;
    if (tid < 64){
        int r = r0 + tid;
        float c = (r < rows) ? matv[r] : 0.f;
        float smin = fdekey(mm2[0]), smax = fdekey(mm2[1]);
        sh_c[tid] = c;
        sh_M[tid] = (c >= 0.f) ? c * smax : c * smin;
    }
    for (int j = tid; j < CS2; j += 256){
        int gj = ch * CS2 + j;
        sh_s[j] = (gj < N_NODE) ? s_v[gj] : 0.f;
    }
    __syncthreads();    // only barrier: cross-wave staging above

    int wv = tid >> 6, lane = tid & 63;
    int half = lane >> 5, c2 = (lane & 31) * 2;
    int am = lane & 15, aq = lane >> 4;

    unsigned roff[8];
    float crow[8], Mrow[8], zacc[8], dacc[8];
    #pragma unroll
    for (int i = 0; i < 8; i++){
        int r = wv*16 + i*2 + half;
        int rr = r0 + r; if (rr >= rows) rr = rows - 1;
        roff[i] = (unsigned)rr * (unsigned)N_NODE;
        crow[i] = sh_c[r]; Mrow[i] = sh_M[r];
        zacc[i] = 0.f; dacc[i] = 0.f;
    }
    f32x4 acc[8];
    #pragma unroll
    for (int n = 0; n < 8; n++) acc[n] = (f32x4){0.f,0.f,0.f,0.f};

    float2 avC[8], avN[8];
    bool inbC = (ch * CS2 + c2) < N_NODE, inbN;
    #pragma unroll
    for (int i = 0; i < 8; i++)
        avC[i] = inbC ? *(const float2*)&adj[roff[i] + ch * CS2 + c2]
                      : make_float2(0.f, 0.f);

    for (int t = 0; t < CS2 / 64; t++){
        int k0g = ch * CS2 + t * 64;
        int k0l = t * 64;
        int k0gn = k0g + 64;
        // 1) Et B-frags for this tile -> registers (before prefetch!)
        bf16x8 bfr[16];
        #pragma unroll
        for (int ks = 0; ks < 2; ks++)
            #pragma unroll
            for (int n = 0; n < 8; n++)
                bfr[ks*8+n] = *(const bf16x8*)&Et[(size_t)(n*16 + am) * KVPAD + k0g + ks*32 + aq*8];
        // 2) next-tile adjacency prefetch
        inbN = (t + 1 < CS2 / 64) && (k0gn + c2) < N_NODE;
        #pragma unroll
        for (int i = 0; i < 8; i++)
            avN[i] = inbN ? *(const float2*)&adj[roff[i] + k0gn + c2]
                          : make_float2(0.f, 0.f);
        // 3) exp / weight / pack (uses avC)
        float2 s2 = *(const float2*)&sh_s[k0l + c2];
        #pragma unroll
        for (int i = 0; i < 8; i++){
            float ex = 0.f, ey = 0.f;
            if (inbC){
                ex = __expf(crow[i]*s2.x - Mrow[i]);
                ey = __expf(crow[i]*s2.y - Mrow[i]);
            }
            zacc[i] += ex + ey;
            float wx = ex * avC[i].x, wy = ey * avC[i].y;
            dacc[i] += wx + wy;
            *(unsigned*)&sh_w[(wv*16 + i*2 + half) * WPAD + c2] =
                (unsigned)f2bf(wx) | ((unsigned)f2bf(wy) << 16);
        }
        // 4) MFMA from registers + wave-private LDS
        #pragma unroll
        for (int ks = 0; ks < 2; ks++){
            bf16x8 afrag = *(const bf16x8*)&sh_w[(wv*16 + am) * WPAD + ks*32 + aq*8];
            #pragma unroll
            for (int n = 0; n < 8; n++)
                acc[n] = __builtin_amdgcn_mfma_f32_16x16x32_bf16(afrag, bfr[ks*8+n], acc[n], 0, 0, 0);
        }
        inbC = inbN;
        #pragma unroll
        for (int i = 0; i < 8; i++) avC[i] = avN[i];
    }
    #pragma unroll
    for (int o = 1; o <= 16; o <<= 1)
        #pragma unroll
        for (int i = 0; i < 8; i++){
            dacc[i] += __shfl_xor(dacc[i], o, 64);
            zacc[i] += __shfl_xor(zacc[i], o, 64);
        }
    if ((lane & 31) == 0){
        #pragma unroll
        for (int i = 0; i < 8; i++){
            int rr = r0 + wv*16 + i*2 + half;
            if (rr < rows){
                float* d2 = part + ((size_t)(baseR + rr) * NCH + ch) * RSTRIDE;
                d2[128] = dacc[i]; d2[129] = zacc[i];
            }
        }
    }
    #pragma unroll
    for (int n = 0; n < 8; n++){
        #pragma unroll
        for (int r = 0; r < 4; r++){
            int rl = wv*16 + aq*4 + r;
            int rr = r0 + rl;
            if (rr < rows){
                float* d2 = part + ((size_t)(baseR + rr) * NCH + ch) * RSTRIDE;
                d2[n*16 + am] = acc[n][r];
            }
        }
    }
}

// ---------------------------------------------------------------------------
// Batched phase-2: reduce big-gate partials over NCH chunks + 4-way inter
// gate from precomputed small-gate buffers. One 128-thr block per row.
struct RIJob {
    const float* e0; float* out; const float* gA; const float* gB;
    const float* W; const float* b; int baseR; int nrows; int row0;
};
struct RIJobs { RIJob j[3]; int njobs; };

__global__ __launch_bounds__(128) void k_reduce_inter(
    RIJobs jobs, const float* __restrict__ part)
{
    __shared__ float sh[4][EMB];
    __shared__ float shW[EMB];
    int b = blockIdx.x;
    int ji = 0;
    for (int q = 1; q < jobs.njobs; q++) if (b >= jobs.j[q].row0) ji = q;
    RIJob J = jobs.j[ji];
    int r = b - J.row0;
    int d = threadIdx.x;
    float num = 0.f, den = 0.f, Z = 0.f;
    for (int c = 0; c < NCH; c++){
        const float* p = part + ((size_t)(J.baseR + r) * NCH + c) * RSTRIDE;
        num += p[d]; den += p[128]; Z += p[129];
    }
    sh[1][d] = num / (den + 1e-8f * Z);
    sh[0][d] = J.e0[(size_t)r * EMB + d];
    sh[2][d] = J.gA[(size_t)r * EMB + d];
    sh[3][d] = J.gB[(size_t)r * EMB + d];
    shW[d] = J.W[d];
    __syncthreads();
    float dots[4];
    #pragma unroll
    for (int g = 0; g < 4; g++){
        float acc = 0.f;
        for (int k = 0; k < EMB; k++) acc += sh[g][k] * shW[k];
        dots[g] = acc;
    }
    float bb = J.b[0];
    float s0 = __expf(dots[0] + bb), s1 = __expf(dots[1] + bb);
    float s2 = __expf(dots[2] + bb), s3 = __expf(dots[3] + bb);
    float inv = 1.f / (s0 + s1 + s2 + s3);
    J.out[(size_t)r * EMB + d] =
        (s0*sh[0][d] + s1*sh[1][d] + s2*sh[2][d] + s3*sh[3][d]) * inv;
}

// ---------------------------------------------------------------------------
extern "C" void kernel_launch(void* const* d_in, const int* in_sizes, int n_in,
                              void* d_out, int out_size, void* d_ws, size_t ws_size,
                              hipStream_t stream)
{
    const int*   adj_idx  = (const int*)d_in[0];
    const float* adj_val  = (const float*)d_in[1];
    const float* a_pv   = (const float*)d_in[2];
    const float* a_vp   = (const float*)d_in[3];
    const float* a_pcb  = (const float*)d_in[4];
    const float* a_cbp  = (const float*)d_in[5];
    const float* a_cbv  = (const float*)d_in[6];
    const float* a_vcb  = (const float*)d_in[7];
    const float* a_pcm  = (const float*)d_in[8];
    const float* a_cmp  = (const float*)d_in[9];
    const float* a_cmv  = (const float*)d_in[10];
    const float* a_vcm  = (const float*)d_in[11];
    const float* a_cbcm = (const float*)d_in[12];
    const float* a_cmcb = (const float*)d_in[13];
    const float* in_item = (const float*)d_in[14];
    const float* in_pri  = (const float*)d_in[15];
    const float* in_cb   = (const float*)d_in[16];
    const float* in_cm   = (const float*)d_in[17];
    const float* m_vp  = (const float*)d_in[18];
    const float* m_vcb = (const float*)d_in[19];
    const float* m_vcm = (const float*)d_in[20];
    const float* m_pv  = (const float*)d_in[21];
    const float* m_pcb = (const float*)d_in[22];
    const float* m_pcm = (const float*)d_in[23];
    const float* m_cbp = (const float*)d_in[24];
    const float* m_cbv = (const float*)d_in[25];
    const float* m_cbcm= (const float*)d_in[26];
    const float* m_cmp = (const float*)d_in[27];
    const float* m_cmv = (const float*)d_in[28];
    const float* m_cmcb= (const float*)d_in[29];
    const float* Wi = (const float*)d_in[30]; const float* bi = (const float*)d_in[31];
    const float* Wp = (const float*)d_in[32]; const float* bp = (const float*)d_in[33];
    const float* Wcb= (const float*)d_in[34]; const float* bcb= (const float*)d_in[35];
    const float* Wcm= (const float*)d_in[36]; const float* bcm= (const float*)d_in[37];

    float* ws = (float*)d_ws;
    size_t off = 0;
    auto alloc = [&](size_t n){ float* p = ws + off; off += (n + 63) & ~(size_t)63; return p; };
    float* buf_item = alloc((size_t)N_NODE * EMB);
    float* buf_pri  = alloc((size_t)N_PRICE * EMB);
    float* buf_cb   = alloc((size_t)N_CB * EMB);
    float* buf_cm   = alloc((size_t)N_CM * EMB);
    float* s_all    = alloc(N_NODE + N_PRICE + N_CB + N_CM);
    unsigned* mm    = (unsigned*)alloc(64);
    float* g1 = alloc((size_t)N_NODE * EMB);
    float* g3 = alloc((size_t)N_NODE * EMB);
    float* part = g1;                       // 650*64*132 = 5.49M floats, alias g1
    unsigned short* et_v = (unsigned short*)g3;  // 13.6 MB, alias g3
    int*   counts = (int*)alloc(N_NODE + 64);
    int*   offs   = (int*)alloc(N_NODE + 64);
    int*   cursor = (int*)alloc(N_NODE + 64);
    int*   scol   = (int*)alloc(NNZE);
    float* sval   = alloc(NNZE);
    unsigned short* et_p  = (unsigned short*)alloc(EMB * 128 / 2);
    unsigned short* et_cb = (unsigned short*)alloc(EMB * 64 / 2);
    unsigned short* et_cm = (unsigned short*)alloc(EMB * 512 / 2);
    float* g_pcb  = alloc((size_t)N_PRICE * EMB);
    float* g_pcm  = alloc((size_t)N_PRICE * EMB);
    float* g_cbp  = alloc((size_t)N_CB * EMB);
    float* g_cbcm = alloc((size_t)N_CB * EMB);
    float* g_cmp  = alloc((size_t)N_CM * EMB);
    float* g_cmcb = alloc((size_t)N_CM * EMB);

    float* out_item = (float*)d_out;
    float* out_pri  = (float*)d_out + (size_t)N_NODE * EMB;

    const float* s_v  = s_all;
    const float* s_p  = s_all + N_NODE;
    const float* s_cb = s_all + N_NODE + N_PRICE;
    const float* s_cm = s_all + N_NODE + N_PRICE + N_CB;

    const int totr = N_NODE + N_PRICE + N_CB + N_CM;

    // ---- CSR build (once; adjacency is layer-invariant) ----
    hipMemsetAsync(counts, 0, N_NODE * sizeof(int), stream);
    k_hist<<<(NNZE + 255)/256, 256, 0, stream>>>(adj_idx, counts);
    k_scan<<<1, SCAN_T, 0, stream>>>(counts, offs, cursor);
    k_scatter<<<(NNZE + 255)/256, 256, 0, stream>>>(adj_idx, adj_idx + NNZE,
                                                    adj_val, cursor, scol, sval);

    for (int layer = 0; layer < 2; layer++){
        const float* cv  = layer ? buf_item : in_item;
        const float* cp  = layer ? buf_pri  : in_pri;
        const float* ccb = layer ? buf_cb   : in_cb;
        const float* ccm = layer ? buf_cm   : in_cm;
        float* ov = layer ? out_item : buf_item;
        float* op = layer ? out_pri  : buf_pri;

        k_rowsum<<<(totr + 3)/4, 256, 0, stream>>>(cv, cp, ccb, ccm, s_all, mm);
        k_minmax<<<(totr + 255)/256, 256, 0, stream>>>(s_all, mm);

        // bf16 transposed operands for p/cb/cm-source gates (tiled transpose)
        k_cast_et_t<<<dim3(2, 2), 256, 0, stream>>>(cp,  et_p,  N_PRICE, 128);
        k_cast_et_t<<<dim3(1, 2), 256, 0, stream>>>(ccb, et_cb, N_CB,    64);
        k_cast_et_t<<<dim3(8, 2), 256, 0, stream>>>(ccm, et_cm, N_CM,    512);

        // batched small gates (MFMA)
        GateJobs gj{};
        int nb = 0, nj = 0;
        auto addjob = [&](const float* adj_, const float* matv_,
                          const unsigned short* Et_, const float* s_,
                          const unsigned* mm2_, float* out_,
                          int K_, int Kpad_, int nrows_){
            gj.j[nj] = GateJob{adj_, matv_, Et_, s_, mm2_, out_,
                               K_, Kpad_, nrows_, nb};
            nb += (nrows_ + 63) / 64; nj++;
        };
        addjob(a_pcb, m_pcb, et_cb, s_cb, mm+4, g_pcb, N_CB,    64, N_PRICE);
        addjob(a_pcm, m_pcm, et_cm, s_cm, mm+6, g_pcm, N_CM,   512, N_PRICE);
        if (layer == 0){
            addjob(a_cbp,  m_cbp,  et_p,  s_p,  mm+2, g_cbp,  N_PRICE, 128, N_CB);
            addjob(a_cbcm, m_cbcm, et_cm, s_cm, mm+6, g_cbcm, N_CM,   512, N_CB);
            addjob(a_cmp,  m_cmp,  et_p,  s_p,  mm+2, g_cmp,  N_PRICE, 128, N_CM);
            addjob(a_cmcb, m_cmcb, et_cb, s_cb, mm+4, g_cmcb, N_CB,    64, N_CM);
        }
        gj.njobs = nj;
        k_gate_batch<<<nb, 256, 0, stream>>>(gj);

        // fused item update (3 intra gates + inter gate)
        FParams fp{};
        fp.g[0] = FGate{a_vp,  m_vp,  et_p,  mm+2, N_PRICE, 128, 0};
        fp.g[1] = FGate{a_vcb, m_vcb, et_cb, mm+4, N_CB,    64,  100};
        fp.g[2] = FGate{a_vcm, m_vcm, et_cm, mm+6, N_CM,    512, 150};
        k_item_fused<<<(N_NODE + 63)/64, 256, 0, stream>>>(
            fp, cv, s_all + N_NODE, Wi, bi, ov);

        k_spmm_csr<<<(N_NODE*64 + 255)/256, 256, 0, stream>>>(offs, scol, sval, cv, ov);

        // item-side bf16 transposed operand (aliases g3, now dead)
        k_cast_et_t<<<dim3(KVPAD/64, 2), 256, 0, stream>>>(cv, et_v, N_NODE, KVPAD);

        k_intra_tv_mfma<<<((N_PRICE + 63)/64) * NCH, 256, 0, stream>>>(
            a_pv, m_pv, et_v, s_v, mm + 0, part, 0, N_PRICE);
        if (layer == 0){
            k_intra_tv_mfma<<<((N_CB + 63)/64) * NCH, 256, 0, stream>>>(
                a_cbv, m_cbv, et_v, s_v, mm + 0, part, N_PRICE, N_CB);
            k_intra_tv_mfma<<<((N_CM + 63)/64) * NCH, 256, 0, stream>>>(
                a_cmv, m_cmv, et_v, s_v, mm + 0, part, N_PRICE + N_CB, N_CM);
        }

        // batched phase-2 reduce + inter
        RIJobs rj{};
        rj.j[0] = RIJob{cp, op, g_pcb, g_pcm, Wp, bp, 0, N_PRICE, 0};
        int nrows_tot = N_PRICE;
        int njr = 1;
        if (layer == 0){
            rj.j[1] = RIJob{ccb, buf_cb, g_cbp, g_cbcm, Wcb, bcb,
                            N_PRICE, N_CB, nrows_tot};
            nrows_tot += N_CB; njr++;
            rj.j[2] = RIJob{ccm, buf_cm, g_cmp, g_cmcb, Wcm, bcm,
                            N_PRICE + N_CB, N_CM, nrows_tot};
            nrows_tot += N_CM; njr++;
        }
        rj.njobs = njr;
        k_reduce_inter<<<nrows_tot, 128, 0, stream>>>(rj, part);
    }
    (void)in_sizes; (void)n_in; (void)out_size; (void)ws_size;
}